// Round 1
// baseline (1140.958 us; speedup 1.0000x reference)
//
#include <hip/hip_runtime.h>
#include <math.h>

#define BB 8
#define NN 2048
#define DD 256
#define TT (BB*NN)      // 16384 tokens
#define DP1 257
#define EPSF 1e-6f

// ---------------- block-wide reductions (256 threads) ----------------
__device__ __forceinline__ float block_sum_256(float v) {
  __shared__ float s[256];
  int t = threadIdx.x;
  s[t] = v;
  __syncthreads();
#pragma unroll
  for (int st = 128; st > 0; st >>= 1) {
    if (t < st) s[t] += s[t + st];
    __syncthreads();
  }
  float r = s[0];
  __syncthreads();   // safe reuse on next call
  return r;
}

__device__ __forceinline__ float block_max_256(float v) {
  __shared__ float s[256];
  int t = threadIdx.x;
  s[t] = v;
  __syncthreads();
#pragma unroll
  for (int st = 128; st > 0; st >>= 1) {
    if (t < st) s[t] = fmaxf(s[t], s[t + st]);
    __syncthreads();
  }
  float r = s[0];
  __syncthreads();
  return r;
}

// ---------------- K1: x_tan = log_map0(x)[1:], vel0 = pt_to_origin spatial ----
__global__ __launch_bounds__(256) void prep_kernel(
    const float* __restrict__ x, const float* __restrict__ xv,
    float* __restrict__ xtan, float* __restrict__ vel0) {
  const int tok = blockIdx.x;
  const int t = threadIdx.x;
  const float* xr = x  + (size_t)tok * DP1;
  const float* vr = xv + (size_t)tok * DP1;
  float x0 = xr[0];
  float sp = xr[1 + t];
  float ss = block_sum_256(sp * sp);
  float n  = sqrtf(fmaxf(ss, EPSF));
  float dd = acoshf(fmaxf(x0, 1.f + EPSF));
  float scl = dd / n;
  xtan[(size_t)tok * DD + t] = scl * sp;
  float coef = -vr[0] / (1.f + x0);
  vel0[(size_t)tok * DD + t] = vr[1 + t] + coef * sp;
}

// ---------------- tiled fp32 GEMM: C[m,n] = sum_k A[m,k]*Wt[n,k] + bias[n] ----
// M implied by grid.x*64; tile 64x64, K-step 16, 4x4 per thread.
__global__ __launch_bounds__(256) void gemm_nt(
    const float* __restrict__ A, const float* __restrict__ Wt,
    const float* __restrict__ bias, float* __restrict__ C,
    int K, int Nc) {
  __shared__ __align__(16) float sA[16][64];
  __shared__ __align__(16) float sB[16][64];
  const int bm = blockIdx.x * 64, bn = blockIdx.y * 64;
  const int t = threadIdx.x;
  const int tx = t & 15, ty = t >> 4;
  const int lr = t >> 2, lk = (t & 3) * 4;
  float acc[4][4] = {};
  for (int k0 = 0; k0 < K; k0 += 16) {
    float4 a4 = *(const float4*)(A  + (size_t)(bm + lr) * K + k0 + lk);
    float4 b4 = *(const float4*)(Wt + (size_t)(bn + lr) * K + k0 + lk);
    __syncthreads();
    sA[lk+0][lr] = a4.x; sA[lk+1][lr] = a4.y; sA[lk+2][lr] = a4.z; sA[lk+3][lr] = a4.w;
    sB[lk+0][lr] = b4.x; sB[lk+1][lr] = b4.y; sB[lk+2][lr] = b4.z; sB[lk+3][lr] = b4.w;
    __syncthreads();
#pragma unroll
    for (int kk = 0; kk < 16; kk++) {
      float4 av = *(const float4*)(&sA[kk][ty * 4]);
      float4 bv = *(const float4*)(&sB[kk][tx * 4]);
      float ar[4] = {av.x, av.y, av.z, av.w};
      float br[4] = {bv.x, bv.y, bv.z, bv.w};
#pragma unroll
      for (int i = 0; i < 4; i++)
#pragma unroll
        for (int j = 0; j < 4; j++)
          acc[i][j] += ar[i] * br[j];
    }
  }
#pragma unroll
  for (int i = 0; i < 4; i++) {
    float4 o;
    float* op = (float*)&o;
#pragma unroll
    for (int j = 0; j < 4; j++)
      op[j] = acc[i][j] + (bias ? bias[bn + tx * 4 + j] : 0.f);
    *(float4*)(C + (size_t)(bm + ty * 4 + i) * Nc + bn + tx * 4) = o;
  }
}

// ---------------- K3: exp-map scaling of q_s/k_s (in place) + scalars --------
__global__ __launch_bounds__(256) void scale_kernel(
    float* __restrict__ q_s, float* __restrict__ k_s,
    const float* __restrict__ q_vel, const float* __restrict__ k_vel,
    float* __restrict__ q0, float* __restrict__ k0,
    float* __restrict__ q_sq, float* __restrict__ k_sq) {
  const int tok = blockIdx.x;
  const int t = threadIdx.x;
  size_t off = (size_t)tok * DD + t;
  float q  = q_s[off],  k  = k_s[off];
  float qv = q_vel[off], kv = k_vel[off];
  float sq  = block_sum_256(q * q);
  float sk  = block_sum_256(k * k);
  float svq = block_sum_256(qv * qv);
  float svk = block_sum_256(kv * kv);
  float nq = sqrtf(fmaxf(sq, EPSF));
  float nk = sqrtf(fmaxf(sk, EPSF));
  q_s[off] = q * (sinhf(nq) / nq);
  k_s[off] = k * (sinhf(nk) / nk);
  if (t == 0) {
    q0[tok] = coshf(nq);
    k0[tok] = coshf(nk);
    q_sq[tok] = svq;
    k_sq[tok] = svk;
  }
}

// ---------------- K4: logits = -(1/tau)*acosh(q0k0 - qk)^2 - pen -------------
__global__ __launch_bounds__(256) void logits_kernel(
    const float* __restrict__ qsp, const float* __restrict__ ksp,
    const float* __restrict__ qvel, const float* __restrict__ kvel,
    const float* __restrict__ q0a, const float* __restrict__ k0a,
    const float* __restrict__ qsqa, const float* __restrict__ ksqa,
    const float* __restrict__ tau, float* __restrict__ attn) {
  const int b  = blockIdx.z;
  const int bn = blockIdx.x * 64;   // query rows
  const int bm = blockIdx.y * 64;   // key cols
  const size_t tb = (size_t)b * NN;
  const float* Q  = qsp  + tb * DD;
  const float* Kk = ksp  + tb * DD;
  const float* Qv = qvel + tb * DD;
  const float* Kv = kvel + tb * DD;
  __shared__ __align__(16) float sQ[16][64], sK[16][64], sQv[16][64], sKv[16][64];
  const int t = threadIdx.x;
  const int tx = t & 15, ty = t >> 4;
  const int lr = t >> 2, lk = (t & 3) * 4;
  float accq[4][4] = {}, accv[4][4] = {};
  for (int k0 = 0; k0 < DD; k0 += 16) {
    float4 q4  = *(const float4*)(Q  + (size_t)(bn + lr) * DD + k0 + lk);
    float4 k4  = *(const float4*)(Kk + (size_t)(bm + lr) * DD + k0 + lk);
    float4 qv4 = *(const float4*)(Qv + (size_t)(bn + lr) * DD + k0 + lk);
    float4 kv4 = *(const float4*)(Kv + (size_t)(bm + lr) * DD + k0 + lk);
    __syncthreads();
    sQ [lk+0][lr] = q4.x;  sQ [lk+1][lr] = q4.y;  sQ [lk+2][lr] = q4.z;  sQ [lk+3][lr] = q4.w;
    sK [lk+0][lr] = k4.x;  sK [lk+1][lr] = k4.y;  sK [lk+2][lr] = k4.z;  sK [lk+3][lr] = k4.w;
    sQv[lk+0][lr] = qv4.x; sQv[lk+1][lr] = qv4.y; sQv[lk+2][lr] = qv4.z; sQv[lk+3][lr] = qv4.w;
    sKv[lk+0][lr] = kv4.x; sKv[lk+1][lr] = kv4.y; sKv[lk+2][lr] = kv4.z; sKv[lk+3][lr] = kv4.w;
    __syncthreads();
#pragma unroll
    for (int kk = 0; kk < 16; kk++) {
      float4 aq = *(const float4*)(&sQ [kk][ty * 4]);
      float4 bk = *(const float4*)(&sK [kk][tx * 4]);
      float4 av = *(const float4*)(&sQv[kk][ty * 4]);
      float4 bv = *(const float4*)(&sKv[kk][tx * 4]);
      float aqr[4] = {aq.x, aq.y, aq.z, aq.w};
      float bkr[4] = {bk.x, bk.y, bk.z, bk.w};
      float avr[4] = {av.x, av.y, av.z, av.w};
      float bvr[4] = {bv.x, bv.y, bv.z, bv.w};
#pragma unroll
      for (int i = 0; i < 4; i++)
#pragma unroll
        for (int j = 0; j < 4; j++) {
          accq[i][j] += aqr[i] * bkr[j];
          accv[i][j] += avr[i] * bvr[j];
        }
    }
  }
  float invt = 1.f / fmaxf(tau[0], 1e-3f);
  float q0r[4], qsr[4], k0c[4], ksc[4];
#pragma unroll
  for (int i = 0; i < 4; i++) {
    q0r[i] = q0a [tb + bn + ty * 4 + i];
    qsr[i] = qsqa[tb + bn + ty * 4 + i];
  }
#pragma unroll
  for (int j = 0; j < 4; j++) {
    k0c[j] = k0a [tb + bm + tx * 4 + j];
    ksc[j] = ksqa[tb + bm + tx * 4 + j];
  }
  size_t base = (size_t)b * NN * NN;
#pragma unroll
  for (int i = 0; i < 4; i++) {
    float4 o;
    float* op = (float*)&o;
#pragma unroll
    for (int j = 0; j < 4; j++) {
      float xv = q0r[i] * k0c[j] - accq[i][j];
      float dL = acoshf(fmaxf(xv, 1.f + EPSF));
      float pen = fmaxf(qsr[i] + ksc[j] - 2.f * accv[i][j], 0.f);
      op[j] = -invt * dL * dL - pen;
    }
    *(float4*)(attn + base + (size_t)(bn + ty * 4 + i) * NN + bm + tx * 4) = o;
  }
}

// ---------------- K5: row softmax over 2048, in place ------------------------
__global__ __launch_bounds__(256) void softmax_kernel(float* __restrict__ attn) {
  const size_t row = blockIdx.x;
  float* p = attn + row * (size_t)NN;
  const int t = threadIdx.x;
  float v[8];
  float mx = -1e30f;
#pragma unroll
  for (int i = 0; i < 8; i++) { v[i] = p[t + 256 * i]; mx = fmaxf(mx, v[i]); }
  mx = block_max_256(mx);
  float s = 0.f;
#pragma unroll
  for (int i = 0; i < 8; i++) { v[i] = expf(v[i] - mx); s += v[i]; }
  s = block_sum_256(s);
  float inv = 1.f / s;
#pragma unroll
  for (int i = 0; i < 8; i++) p[t + 256 * i] = v[i] * inv;
}

// ---------------- K6: agg = attn @ v_s  (NN GEMM) ----------------------------
__global__ __launch_bounds__(256) void pv_kernel(
    const float* __restrict__ attn, const float* __restrict__ vs,
    float* __restrict__ agg) {
  const int b  = blockIdx.z;
  const int bn = blockIdx.x * 64;   // rows n
  const int bd = blockIdx.y * 64;   // cols d
  const float* A  = attn + (size_t)b * NN * NN;
  const float* Vv = vs   + (size_t)b * NN * DD;
  __shared__ __align__(16) float sA[16][64], sB[16][64];
  const int t = threadIdx.x;
  const int tx = t & 15, ty = t >> 4;
  const int lr = t >> 2, lk = (t & 3) * 4;
  float acc[4][4] = {};
  for (int k0 = 0; k0 < NN; k0 += 16) {
    float4 a4 = *(const float4*)(A + (size_t)(bn + lr) * NN + k0 + lk);
    float4 b4 = *(const float4*)(Vv + (size_t)(k0 + (t >> 4)) * DD + bd + (t & 15) * 4);
    __syncthreads();
    sA[lk+0][lr] = a4.x; sA[lk+1][lr] = a4.y; sA[lk+2][lr] = a4.z; sA[lk+3][lr] = a4.w;
    *(float4*)(&sB[t >> 4][(t & 15) * 4]) = b4;
    __syncthreads();
#pragma unroll
    for (int kk = 0; kk < 16; kk++) {
      float4 av = *(const float4*)(&sA[kk][ty * 4]);
      float4 bv = *(const float4*)(&sB[kk][tx * 4]);
      float ar[4] = {av.x, av.y, av.z, av.w};
      float br[4] = {bv.x, bv.y, bv.z, bv.w};
#pragma unroll
      for (int i = 0; i < 4; i++)
#pragma unroll
        for (int j = 0; j < 4; j++)
          acc[i][j] += ar[i] * br[j];
    }
  }
#pragma unroll
  for (int i = 0; i < 4; i++) {
    float4 o;
    float* op = (float*)&o;
#pragma unroll
    for (int j = 0; j < 4; j++) op[j] = acc[i][j];
    *(float4*)(agg + (size_t)(b * NN + bn + ty * 4 + i) * DD + bd + tx * 4) = o;
  }
}

// ---------------- K7: z = exp_map0(pad(agg)) --------------------------------
__global__ __launch_bounds__(256) void zmap_kernel(
    const float* __restrict__ agg, float* __restrict__ z) {
  const int tok = blockIdx.x;
  const int t = threadIdx.x;
  float a = agg[(size_t)tok * DD + t];
  float ss = block_sum_256(a * a);
  float n = sqrtf(fmaxf(ss, EPSF));
  float sc = sinhf(n) / n;
  if (t == 0) z[(size_t)tok * DP1] = coshf(n);
  z[(size_t)tok * DP1 + 1 + t] = sc * a;
}

// ---------------- launch -----------------------------------------------------
extern "C" void kernel_launch(void* const* d_in, const int* in_sizes, int n_in,
                              void* d_out, int out_size, void* d_ws, size_t ws_size,
                              hipStream_t stream) {
  const float* x   = (const float*)d_in[0];
  const float* xv  = (const float*)d_in[1];
  const float* Wq  = (const float*)d_in[2];
  const float* bq  = (const float*)d_in[3];
  const float* Wk  = (const float*)d_in[4];
  const float* bk  = (const float*)d_in[5];
  const float* Wv  = (const float*)d_in[6];
  const float* bv  = (const float*)d_in[7];
  const float* tau = (const float*)d_in[8];
  float* out = (float*)d_out;
  float* ws  = (float*)d_ws;

  const size_t TD = (size_t)TT * DD;
  float* vel0  = ws;             // reused as agg after the vel GEMMs
  float* q_s   = ws + TD;
  float* k_s   = ws + 2 * TD;
  float* v_s   = ws + 3 * TD;
  float* q_vel = ws + 4 * TD;
  float* k_vel = ws + 5 * TD;
  float* q0    = ws + 6 * TD;
  float* k0    = q0 + TT;
  float* q_sq  = q0 + 2 * TT;
  float* k_sq  = q0 + 3 * TT;

  float* z_out    = out;
  float* attn_out = out + (size_t)TT * DP1;
  float* xtan_out = attn_out + (size_t)BB * NN * NN;

  prep_kernel<<<TT, 256, 0, stream>>>(x, xv, xtan_out, vel0);

  dim3 g1(TT / 64, DD / 64);
  gemm_nt<<<g1, 256, 0, stream>>>(xtan_out, Wq, bq, q_s,   DD, DD);
  gemm_nt<<<g1, 256, 0, stream>>>(xtan_out, Wk, bk, k_s,   DD, DD);
  gemm_nt<<<g1, 256, 0, stream>>>(xtan_out, Wv, bv, v_s,   DD, DD);
  gemm_nt<<<g1, 256, 0, stream>>>(vel0,     Wq, bq, q_vel, DD, DD);
  gemm_nt<<<g1, 256, 0, stream>>>(vel0,     Wk, bk, k_vel, DD, DD);

  scale_kernel<<<TT, 256, 0, stream>>>(q_s, k_s, q_vel, k_vel, q0, k0, q_sq, k_sq);

  logits_kernel<<<dim3(NN / 64, NN / 64, BB), 256, 0, stream>>>(
      q_s, k_s, q_vel, k_vel, q0, k0, q_sq, k_sq, tau, attn_out);

  softmax_kernel<<<TT, 256, 0, stream>>>(attn_out);

  pv_kernel<<<dim3(NN / 64, DD / 64, BB), 256, 0, stream>>>(attn_out, v_s, vel0);

  zmap_kernel<<<TT, 256, 0, stream>>>(vel0, z_out);
}

// Round 2
// 394.286 us; speedup vs baseline: 2.8937x; 2.8937x over previous
//
#include <hip/hip_runtime.h>
#include <math.h>

#define BB 8
#define NN 2048
#define DD 256
#define TT (BB*NN)      // 16384 tokens
#define DP1 257
#define EPSF 1e-6f

typedef _Float16 f16;
typedef __attribute__((ext_vector_type(8))) _Float16 f16x8;
typedef __attribute__((ext_vector_type(4))) float f32x4;

__device__ __forceinline__ f32x4 mfma16(f16x8 a, f16x8 b, f32x4 c) {
  return __builtin_amdgcn_mfma_f32_16x16x32_f16(a, b, c, 0, 0, 0);
}

// ---------------- block-wide reductions (256 threads) ----------------
__device__ __forceinline__ float block_sum_256(float v) {
  __shared__ float s[256];
  int t = threadIdx.x;
  s[t] = v;
  __syncthreads();
#pragma unroll
  for (int st = 128; st > 0; st >>= 1) {
    if (t < st) s[t] += s[t + st];
    __syncthreads();
  }
  float r = s[0];
  __syncthreads();
  return r;
}

__device__ __forceinline__ float block_max_256(float v) {
  __shared__ float s[256];
  int t = threadIdx.x;
  s[t] = v;
  __syncthreads();
#pragma unroll
  for (int st = 128; st > 0; st >>= 1) {
    if (t < st) s[t] = fmaxf(s[t], s[t + st]);
    __syncthreads();
  }
  float r = s[0];
  __syncthreads();
  return r;
}

// ---------------- K1: x_tan fp32 (output) + f16 copies ----------------------
__global__ __launch_bounds__(256) void prep_kernel(
    const float* __restrict__ x, const float* __restrict__ xv,
    float* __restrict__ xtan, f16* __restrict__ xtan_h, f16* __restrict__ vel0_h) {
  const int tok = blockIdx.x;
  const int t = threadIdx.x;
  const float* xr = x  + (size_t)tok * DP1;
  const float* vr = xv + (size_t)tok * DP1;
  float x0 = xr[0];
  float sp = xr[1 + t];
  float ss = block_sum_256(sp * sp);
  float n  = sqrtf(fmaxf(ss, EPSF));
  float dd = acoshf(fmaxf(x0, 1.f + EPSF));
  float xt = (dd / n) * sp;
  xtan[(size_t)tok * DD + t] = xt;
  xtan_h[(size_t)tok * DD + t] = (f16)xt;
  float coef = -vr[0] / (1.f + x0);
  vel0_h[(size_t)tok * DD + t] = (f16)(vr[1 + t] + coef * sp);
}

// ---------------- weight cast fp32 -> f16 ------------------------------------
__global__ __launch_bounds__(256) void wcast_kernel(
    const float* __restrict__ Wq, const float* __restrict__ Wk,
    const float* __restrict__ Wv, f16* __restrict__ Wh) {
  const int m = blockIdx.y;
  const int i = blockIdx.x * 256 + threadIdx.x;
  const float* W = (m == 0) ? Wq : ((m == 1) ? Wk : Wv);
  Wh[(size_t)m * DD * DD + i] = (f16)W[i];
}

// ---------------- MFMA GEMM: C[m,n] = sum_k A[m,k]*B[n,k] (+bias[n]) ---------
// 128x128 tile, 4 waves (2x2), BK=32, 16x16x32 f16 MFMA.
// OUTV: 0 = f16 row-major (+bias), 1 = f16 transposed per-batch (+bias),
//       2 = fp32 row-major (+bias if nonnull)
// A32:  A operand source is fp32 (converted during staging)
template<int OUTV, bool A32>
__global__ __launch_bounds__(256, 2) void gemm_mfma(
    const void* __restrict__ Aptr, size_t a_bstride, int lda,
    const f16* __restrict__ Bh, size_t b_bstride, int ldb,
    const float* __restrict__ bias, int K,
    void* __restrict__ Cptr, size_t c_bstride, int ldc) {
  __shared__ __align__(16) f16 sA[128 * 32];
  __shared__ __align__(16) f16 sB[128 * 32];
  const int tid = threadIdx.x;
  const int bz = blockIdx.z;
  const int bm = blockIdx.x * 128;
  const int bn = blockIdx.y * 128;
  const int w = tid >> 6, l = tid & 63;
  const int wr = w >> 1, wc = w & 1;
  f32x4 acc[4][4] = {};

  const f16* Bbase = Bh + (size_t)bz * b_bstride + (size_t)bn * ldb;

  for (int k0 = 0; k0 < K; k0 += 32) {
    __syncthreads();
    if (A32) {
      const float* A = (const float*)Aptr + (size_t)bz * a_bstride + (size_t)bm * lda + k0;
#pragma unroll
      for (int p = 0; p < 2; p++) {
        int u = tid + p * 256, row = u >> 2, cu = u & 3;
        const float* s = A + (size_t)row * lda + cu * 8;
        float4 xa = *(const float4*)s;
        float4 xb = *(const float4*)(s + 4);
        f16x8 v = {(f16)xa.x, (f16)xa.y, (f16)xa.z, (f16)xa.w,
                   (f16)xb.x, (f16)xb.y, (f16)xb.z, (f16)xb.w};
        *(f16x8*)(sA + row * 32 + cu * 8) = v;
      }
    } else {
      const f16* A = (const f16*)Aptr + (size_t)bz * a_bstride + (size_t)bm * lda + k0;
#pragma unroll
      for (int p = 0; p < 2; p++) {
        int u = tid + p * 256, row = u >> 2, cu = u & 3;
        *(f16x8*)(sA + row * 32 + cu * 8) = *(const f16x8*)(A + (size_t)row * lda + cu * 8);
      }
    }
    {
      const f16* Bp = Bbase + k0;
#pragma unroll
      for (int p = 0; p < 2; p++) {
        int u = tid + p * 256, row = u >> 2, cu = u & 3;
        *(f16x8*)(sB + row * 32 + cu * 8) = *(const f16x8*)(Bp + (size_t)row * ldb + cu * 8);
      }
    }
    __syncthreads();
    f16x8 af[4], bf[4];
#pragma unroll
    for (int i = 0; i < 4; i++)
      af[i] = *(const f16x8*)(sA + (wr * 64 + i * 16 + (l & 15)) * 32 + (l >> 4) * 8);
#pragma unroll
    for (int j = 0; j < 4; j++)
      bf[j] = *(const f16x8*)(sB + (wc * 64 + j * 16 + (l & 15)) * 32 + (l >> 4) * 8);
#pragma unroll
    for (int i = 0; i < 4; i++)
#pragma unroll
      for (int j = 0; j < 4; j++)
        acc[i][j] = mfma16(af[i], bf[j], acc[i][j]);
  }

  // epilogue: C/D layout col=lane&15, row=(lane>>4)*4+r
  const int rl = (l >> 4) * 4, cl = l & 15;
#pragma unroll
  for (int i = 0; i < 4; i++) {
#pragma unroll
    for (int j = 0; j < 4; j++) {
      const int col = bn + wc * 64 + j * 16 + cl;
      const float bv = bias ? bias[col] : 0.f;
      const int row0 = bm + wr * 64 + i * 16 + rl;
      if (OUTV == 0) {
        f16* C = (f16*)Cptr + (size_t)bz * c_bstride;
#pragma unroll
        for (int r = 0; r < 4; r++)
          C[(size_t)(row0 + r) * ldc + col] = (f16)(acc[i][j][r] + bv);
      } else if (OUTV == 1) {
        // transposed f16: vT[(batch*DD + col)*NN + row%NN], 4 contiguous rows
        const int bb = row0 >> 11;
        __align__(8) f16 tmp[4];
#pragma unroll
        for (int r = 0; r < 4; r++) tmp[r] = (f16)(acc[i][j][r] + bv);
        f16* dst = (f16*)Cptr + ((size_t)(bb * DD + col)) * NN + (row0 & (NN - 1));
        *(uint2*)dst = *(const uint2*)tmp;
      } else {
        float* C = (float*)Cptr + (size_t)bz * c_bstride;
#pragma unroll
        for (int r = 0; r < 4; r++)
          C[(size_t)(row0 + r) * ldc + col] = acc[i][j][r] + bv;
      }
    }
  }
}

// ---------------- scale: norms in fp32, write scaled f16 q/k + scalars -------
__global__ __launch_bounds__(256) void scale_kernel(
    const float* __restrict__ q_s, const float* __restrict__ k_s,
    const f16* __restrict__ qvh, const f16* __restrict__ kvh,
    f16* __restrict__ qh, f16* __restrict__ kh,
    float* __restrict__ q0, float* __restrict__ k0v,
    float* __restrict__ q_sq, float* __restrict__ k_sq) {
  const int tok = blockIdx.x;
  const int t = threadIdx.x;
  size_t off = (size_t)tok * DD + t;
  float q  = q_s[off], k = k_s[off];
  float qv = (float)qvh[off], kv = (float)kvh[off];
  float sq  = block_sum_256(q * q);
  float sk  = block_sum_256(k * k);
  float svq = block_sum_256(qv * qv);
  float svk = block_sum_256(kv * kv);
  float nq = sqrtf(fmaxf(sq, EPSF));
  float nk = sqrtf(fmaxf(sk, EPSF));
  qh[off] = (f16)(q * (sinhf(nq) / nq));
  kh[off] = (f16)(k * (sinhf(nk) / nk));
  if (t == 0) {
    q0[tok] = coshf(nq);
    k0v[tok] = coshf(nk);
    q_sq[tok] = svq;
    k_sq[tok] = svk;
  }
}

// ---------------- logits: dual MFMA GEMM + acosh/pen epilogue ----------------
__global__ __launch_bounds__(256, 2) void logits_mfma(
    const f16* __restrict__ qh, const f16* __restrict__ kh,
    const f16* __restrict__ qvh, const f16* __restrict__ kvh,
    const float* __restrict__ q0a, const float* __restrict__ k0a,
    const float* __restrict__ qsqa, const float* __restrict__ ksqa,
    const float* __restrict__ tau, float* __restrict__ attn) {
  __shared__ __align__(16) f16 sQ[128 * 32], sK[128 * 32], sQv[128 * 32], sKv[128 * 32];
  const int tid = threadIdx.x;
  const int b = blockIdx.z;
  const int bq = blockIdx.x * 128;   // query rows
  const int bk = blockIdx.y * 128;   // key cols
  const size_t tb = (size_t)b * NN;
  const f16* Q  = qh  + (tb + bq) * DD;
  const f16* Kp = kh  + (tb + bk) * DD;
  const f16* Qv = qvh + (tb + bq) * DD;
  const f16* Kv = kvh + (tb + bk) * DD;
  const int w = tid >> 6, l = tid & 63;
  const int wr = w >> 1, wc = w & 1;
  f32x4 accq[4][4] = {}, accv[4][4] = {};

  for (int k0 = 0; k0 < DD; k0 += 32) {
    __syncthreads();
#pragma unroll
    for (int p = 0; p < 2; p++) {
      int u = tid + p * 256, row = u >> 2, cu = u & 3;
      size_t go = (size_t)row * DD + k0 + cu * 8;
      int so = row * 32 + cu * 8;
      *(f16x8*)(sQ  + so) = *(const f16x8*)(Q  + go);
      *(f16x8*)(sK  + so) = *(const f16x8*)(Kp + go);
      *(f16x8*)(sQv + so) = *(const f16x8*)(Qv + go);
      *(f16x8*)(sKv + so) = *(const f16x8*)(Kv + go);
    }
    __syncthreads();
    {
      f16x8 a[4], bb[4];
#pragma unroll
      for (int i = 0; i < 4; i++)
        a[i] = *(const f16x8*)(sQ + (wr * 64 + i * 16 + (l & 15)) * 32 + (l >> 4) * 8);
#pragma unroll
      for (int j = 0; j < 4; j++)
        bb[j] = *(const f16x8*)(sK + (wc * 64 + j * 16 + (l & 15)) * 32 + (l >> 4) * 8);
#pragma unroll
      for (int i = 0; i < 4; i++)
#pragma unroll
        for (int j = 0; j < 4; j++)
          accq[i][j] = mfma16(a[i], bb[j], accq[i][j]);
    }
    {
      f16x8 a[4], bb[4];
#pragma unroll
      for (int i = 0; i < 4; i++)
        a[i] = *(const f16x8*)(sQv + (wr * 64 + i * 16 + (l & 15)) * 32 + (l >> 4) * 8);
#pragma unroll
      for (int j = 0; j < 4; j++)
        bb[j] = *(const f16x8*)(sKv + (wc * 64 + j * 16 + (l & 15)) * 32 + (l >> 4) * 8);
#pragma unroll
      for (int i = 0; i < 4; i++)
#pragma unroll
        for (int j = 0; j < 4; j++)
          accv[i][j] = mfma16(a[i], bb[j], accv[i][j]);
    }
  }

  const int rl = (l >> 4) * 4, cl = l & 15;
  const float invt = 1.f / fmaxf(tau[0], 1e-3f);
  float k0c[4], ksc[4];
#pragma unroll
  for (int j = 0; j < 4; j++) {
    int col = bk + wc * 64 + j * 16 + cl;
    k0c[j] = k0a[tb + col];
    ksc[j] = ksqa[tb + col];
  }
  const size_t obase = (size_t)b * NN * NN;
#pragma unroll
  for (int i = 0; i < 4; i++) {
#pragma unroll
    for (int r = 0; r < 4; r++) {
      const int row = bq + wr * 64 + i * 16 + rl + r;
      const float q0 = q0a[tb + row];
      const float qs = qsqa[tb + row];
#pragma unroll
      for (int j = 0; j < 4; j++) {
        float xv = fmaxf(q0 * k0c[j] - accq[i][j][r], 1.f + EPSF);
        float dL = acoshf(xv);
        float pen = fmaxf(qs + ksc[j] - 2.f * accv[i][j][r], 0.f);
        const int col = bk + wc * 64 + j * 16 + cl;
        attn[obase + (size_t)row * NN + col] = -invt * dL * dL - pen;
      }
    }
  }
}

// ---------------- softmax over 2048, in place (fp32, d_out) ------------------
__global__ __launch_bounds__(256) void softmax_kernel(float* __restrict__ attn) {
  const size_t row = blockIdx.x;
  float* p = attn + row * (size_t)NN;
  const int t = threadIdx.x;
  float v[8];
  float mx = -1e30f;
#pragma unroll
  for (int i = 0; i < 8; i++) { v[i] = p[t + 256 * i]; mx = fmaxf(mx, v[i]); }
  mx = block_max_256(mx);
  float s = 0.f;
#pragma unroll
  for (int i = 0; i < 8; i++) { v[i] = expf(v[i] - mx); s += v[i]; }
  s = block_sum_256(s);
  float inv = 1.f / s;
#pragma unroll
  for (int i = 0; i < 8; i++) p[t + 256 * i] = v[i] * inv;
}

// ---------------- K7: z = exp_map0(pad(agg)) --------------------------------
__global__ __launch_bounds__(256) void zmap_kernel(
    const float* __restrict__ agg, float* __restrict__ z) {
  const int tok = blockIdx.x;
  const int t = threadIdx.x;
  float a = agg[(size_t)tok * DD + t];
  float ss = block_sum_256(a * a);
  float n = sqrtf(fmaxf(ss, EPSF));
  float sc = sinhf(n) / n;
  if (t == 0) z[(size_t)tok * DP1] = coshf(n);
  z[(size_t)tok * DP1 + 1 + t] = sc * a;
}

// ---------------- launch -----------------------------------------------------
extern "C" void kernel_launch(void* const* d_in, const int* in_sizes, int n_in,
                              void* d_out, int out_size, void* d_ws, size_t ws_size,
                              hipStream_t stream) {
  const float* x   = (const float*)d_in[0];
  const float* xv  = (const float*)d_in[1];
  const float* Wq  = (const float*)d_in[2];
  const float* bq  = (const float*)d_in[3];
  const float* Wk  = (const float*)d_in[4];
  const float* bk  = (const float*)d_in[5];
  const float* Wv  = (const float*)d_in[6];
  const float* bv  = (const float*)d_in[7];
  const float* tau = (const float*)d_in[8];
  float* out = (float*)d_out;
  char* ws = (char*)d_ws;

  const size_t TD4 = (size_t)TT * DD * 4;   // 16 MB fp32 panel
  const size_t TD2 = (size_t)TT * DD * 2;   // 8 MB f16 panel

  float* q_s32  = (float*)(ws);                       // also reused as agg
  float* k_s32  = (float*)(ws + TD4);
  f16*   qh     = (f16*)(ws + 2 * TD4);
  f16*   kh     = (f16*)(ws + 2 * TD4 + TD2);
  f16*   qvh    = (f16*)(ws + 2 * TD4 + 2 * TD2);
  f16*   kvh    = (f16*)(ws + 2 * TD4 + 3 * TD2);
  f16*   xtan_h = (f16*)(ws + 2 * TD4 + 4 * TD2);
  f16*   vel0_h = (f16*)(ws + 2 * TD4 + 5 * TD2);
  f16*   vT     = (f16*)(ws + 2 * TD4 + 6 * TD2);
  f16*   Wh     = (f16*)(ws + 2 * TD4 + 7 * TD2);
  float* q0     = (float*)(ws + 2 * TD4 + 7 * TD2 + 3 * DD * DD * 2);
  float* k0v    = q0 + TT;
  float* q_sq   = q0 + 2 * TT;
  float* k_sq   = q0 + 3 * TT;
  float* agg    = q_s32;   // alias: q_s32 dead after scale_kernel

  f16* Wqh = Wh;
  f16* Wkh = Wh + DD * DD;
  f16* Wvh = Wh + 2 * DD * DD;

  float* z_out    = out;
  float* attn_out = out + (size_t)TT * DP1;
  float* xtan_out = attn_out + (size_t)BB * NN * NN;

  prep_kernel<<<TT, 256, 0, stream>>>(x, xv, xtan_out, xtan_h, vel0_h);
  wcast_kernel<<<dim3(DD * DD / 256, 3), 256, 0, stream>>>(Wq, Wk, Wv, Wh);

  dim3 g1(TT / 128, DD / 128, 1);
  gemm_mfma<2, false><<<g1, 256, 0, stream>>>(xtan_h, 0, DD, Wqh, 0, DD, bq, DD, q_s32, 0, DD);
  gemm_mfma<2, false><<<g1, 256, 0, stream>>>(xtan_h, 0, DD, Wkh, 0, DD, bk, DD, k_s32, 0, DD);
  gemm_mfma<0, false><<<g1, 256, 0, stream>>>(vel0_h, 0, DD, Wqh, 0, DD, bq, DD, qvh, 0, DD);
  gemm_mfma<0, false><<<g1, 256, 0, stream>>>(vel0_h, 0, DD, Wkh, 0, DD, bk, DD, kvh, 0, DD);
  gemm_mfma<1, false><<<g1, 256, 0, stream>>>(xtan_h, 0, DD, Wvh, 0, DD, bv, DD, vT, 0, 0);

  scale_kernel<<<TT, 256, 0, stream>>>(q_s32, k_s32, qvh, kvh, qh, kh, q0, k0v, q_sq, k_sq);

  logits_mfma<<<dim3(NN / 128, NN / 128, BB), 256, 0, stream>>>(
      qh, kh, qvh, kvh, q0, k0v, q_sq, k_sq, tau, attn_out);

  softmax_kernel<<<TT, 256, 0, stream>>>(attn_out);

  // PV: agg[b,n,d] = sum_m attn[b,n,m] * vT[b,d,m]
  gemm_mfma<2, true><<<dim3(NN / 128, DD / 128, BB), 256, 0, stream>>>(
      attn_out, (size_t)NN * NN, NN, vT, (size_t)DD * NN, NN, nullptr, NN,
      agg, (size_t)NN * DD, DD);

  zmap_kernel<<<TT, 256, 0, stream>>>(agg, z_out);
}

// Round 3
// 274.056 us; speedup vs baseline: 4.1632x; 1.4387x over previous
//
#include <hip/hip_runtime.h>
#include <math.h>

#define BB 8
#define NN 2048
#define DD 256
#define TT (BB*NN)      // 16384 tokens
#define DP1 257
#define EPSF 1e-6f

typedef _Float16 f16;
typedef __attribute__((ext_vector_type(8))) _Float16 f16x8;
typedef __attribute__((ext_vector_type(4))) float f32x4;

__device__ __forceinline__ f32x4 mfma16(f16x8 a, f16x8 b, f32x4 c) {
  return __builtin_amdgcn_mfma_f32_16x16x32_f16(a, b, c, 0, 0, 0);
}

// async global->LDS, 16B per lane. l must be the wave-uniform base;
// HW writes base + lane*16.
__device__ __forceinline__ void gll16(const f16* g, f16* l) {
  __builtin_amdgcn_global_load_lds(
      (const __attribute__((address_space(1))) void*)g,
      (__attribute__((address_space(3))) void*)l, 16, 0, 0);
}

// ---------------- block-wide reductions (256 threads) ----------------
__device__ __forceinline__ float block_sum_256(float v) {
  __shared__ float s[256];
  int t = threadIdx.x;
  s[t] = v;
  __syncthreads();
#pragma unroll
  for (int st = 128; st > 0; st >>= 1) {
    if (t < st) s[t] += s[t + st];
    __syncthreads();
  }
  float r = s[0];
  __syncthreads();
  return r;
}

__device__ __forceinline__ float block_max_256(float v) {
  __shared__ float s[256];
  int t = threadIdx.x;
  s[t] = v;
  __syncthreads();
#pragma unroll
  for (int st = 128; st > 0; st >>= 1) {
    if (t < st) s[t] = fmaxf(s[t], s[t + st]);
    __syncthreads();
  }
  float r = s[0];
  __syncthreads();
  return r;
}

// ---------------- K1: x_tan fp32 (output) + f16 copies ----------------------
__global__ __launch_bounds__(256) void prep_kernel(
    const float* __restrict__ x, const float* __restrict__ xv,
    float* __restrict__ xtan, f16* __restrict__ xtan_h, f16* __restrict__ vel0_h) {
  const int tok = blockIdx.x;
  const int t = threadIdx.x;
  const float* xr = x  + (size_t)tok * DP1;
  const float* vr = xv + (size_t)tok * DP1;
  float x0 = xr[0];
  float sp = xr[1 + t];
  float ss = block_sum_256(sp * sp);
  float n  = sqrtf(fmaxf(ss, EPSF));
  float dd = acoshf(fmaxf(x0, 1.f + EPSF));
  float xt = (dd / n) * sp;
  xtan[(size_t)tok * DD + t] = xt;
  xtan_h[(size_t)tok * DD + t] = (f16)xt;
  float coef = -vr[0] / (1.f + x0);
  vel0_h[(size_t)tok * DD + t] = (f16)(vr[1 + t] + coef * sp);
}

// ---------------- weight cast fp32 -> f16, Wh = [Wq;Wk;Wv] 768x256 ----------
__global__ __launch_bounds__(256) void wcast_kernel(
    const float* __restrict__ Wq, const float* __restrict__ Wk,
    const float* __restrict__ Wv, f16* __restrict__ Wh) {
  const int m = blockIdx.y;
  const int i = blockIdx.x * 256 + threadIdx.x;
  const float* W = (m == 0) ? Wq : ((m == 1) ? Wk : Wv);
  Wh[(size_t)m * DD * DD + i] = (f16)W[i];
}

// ---------------- MFMA GEMM: C[m,n] = sum_k A[m,k]*B[n,k] (+bias[n]) ---------
// TM x 128 tile, 4 waves, BK=32, 16x16x32 f16 MFMA.
// N segmented in 256-col chunks; per-seg out ptr / bias / type:
//   type 0 = f16 rm (ldc=256), 1 = f16 transposed per-batch, 2 = f32 rm (ldc=256)
// A32: A source fp32, reg-staged with convert. Else f16 via global_load_lds.
template<int TM, bool A32>
__global__ __launch_bounds__(256, 2) void gemm_mfma(
    const void* __restrict__ Aptr, size_t a_bstride, int lda,
    const f16* __restrict__ B, size_t b_bstride, int ldb, int K,
    void* o0, void* o1, void* o2,
    const float* b0, const float* b1, const float* b2,
    int t0, int t1, int t2, size_t c_bstride) {
  constexpr int WC_N = (TM == 128) ? 2 : 4;   // waves along N
  constexpr int WCW  = 128 / WC_N;            // wave col width
  constexpr int NJ   = WCW / 16;
  constexpr int PA   = TM / 64;
  __shared__ __align__(16) f16 sA[TM * 32];
  __shared__ __align__(16) f16 sB[128 * 32];
  const int tid = threadIdx.x;
  const int bz = blockIdx.z;
  const int bm = blockIdx.x * TM;
  const int bn = blockIdx.y * 128;
  const int w = tid >> 6, l = tid & 63;
  const int wr = (TM == 128) ? (w >> 1) : 0;
  const int wc = (TM == 128) ? (w & 1) : w;
  f32x4 acc[4][NJ] = {};
  const f16* Bb = B + (size_t)bz * b_bstride + (size_t)bn * ldb;

  for (int k0 = 0; k0 < K; k0 += 32) {
    __syncthreads();
    if (A32) {
      const float* A = (const float*)Aptr + (size_t)bz * a_bstride + (size_t)bm * lda + k0;
#pragma unroll
      for (int p = 0; p < PA; p++) {
        int u = tid + p * 256, row = u >> 2, cu = u & 3;
        const float* s = A + (size_t)row * lda + cu * 8;
        float4 xa = *(const float4*)s;
        float4 xb = *(const float4*)(s + 4);
        f16x8 v = {(f16)xa.x, (f16)xa.y, (f16)xa.z, (f16)xa.w,
                   (f16)xb.x, (f16)xb.y, (f16)xb.z, (f16)xb.w};
        *(f16x8*)(sA + u * 8) = v;
      }
    } else {
      const f16* A = (const f16*)Aptr + (size_t)bz * a_bstride + (size_t)bm * lda + k0;
#pragma unroll
      for (int p = 0; p < PA; p++) {
        int u = tid + p * 256, row = u >> 2, cu = u & 3;
        gll16(A + (size_t)row * lda + cu * 8, sA + (size_t)(w * 64 + p * 256) * 8);
      }
    }
#pragma unroll
    for (int p = 0; p < 2; p++) {
      int u = tid + p * 256, row = u >> 2, cu = u & 3;
      gll16(Bb + (size_t)row * ldb + k0 + cu * 8, sB + (size_t)(w * 64 + p * 256) * 8);
    }
    __syncthreads();
    f16x8 af[4], bf[NJ];
#pragma unroll
    for (int i = 0; i < 4; i++)
      af[i] = *(const f16x8*)(sA + (wr * 64 + i * 16 + (l & 15)) * 32 + (l >> 4) * 8);
#pragma unroll
    for (int j = 0; j < NJ; j++)
      bf[j] = *(const f16x8*)(sB + (wc * WCW + j * 16 + (l & 15)) * 32 + (l >> 4) * 8);
#pragma unroll
    for (int i = 0; i < 4; i++)
#pragma unroll
      for (int j = 0; j < NJ; j++)
        acc[i][j] = mfma16(af[i], bf[j], acc[i][j]);
  }

  // epilogue: C/D layout col=lane&15, row=(lane>>4)*4+r
  const int seg = bn >> 8;
  void* optr = (seg == 0) ? o0 : ((seg == 1) ? o1 : o2);
  const float* bias = (seg == 0) ? b0 : ((seg == 1) ? b1 : b2);
  const int ot = (seg == 0) ? t0 : ((seg == 1) ? t1 : t2);
  const int rl = (l >> 4) * 4, cl = l & 15;
#pragma unroll
  for (int i = 0; i < 4; i++) {
#pragma unroll
    for (int j = 0; j < NJ; j++) {
      const int col = (bn & 255) + wc * WCW + j * 16 + cl;
      const float bv = bias ? bias[col] : 0.f;
      const int row0 = bm + wr * 64 + i * 16 + rl;
      if (ot == 0) {
        f16* C = (f16*)optr;
#pragma unroll
        for (int r = 0; r < 4; r++)
          C[(size_t)(row0 + r) * DD + col] = (f16)(acc[i][j][r] + bv);
      } else if (ot == 1) {
        __align__(8) f16 tmp[4];
#pragma unroll
        for (int r = 0; r < 4; r++) tmp[r] = (f16)(acc[i][j][r] + bv);
        f16* dst = (f16*)optr + ((size_t)((row0 >> 11) * DD + col)) * NN + (row0 & (NN - 1));
        *(uint2*)dst = *(const uint2*)tmp;
      } else {
        float* C = (float*)optr + (size_t)bz * c_bstride;
#pragma unroll
        for (int r = 0; r < 4; r++)
          C[(size_t)(row0 + r) * DD + col] = acc[i][j][r] + bv;
      }
    }
  }
}

// ---------------- scale: norms in fp32, write scaled f16 q/k + scalars -------
__global__ __launch_bounds__(256) void scale_kernel(
    const float* __restrict__ q_s, const float* __restrict__ k_s,
    const f16* __restrict__ qvh, const f16* __restrict__ kvh,
    f16* __restrict__ qh, f16* __restrict__ kh,
    float* __restrict__ q0, float* __restrict__ k0v,
    float* __restrict__ q_sq, float* __restrict__ k_sq) {
  const int tok = blockIdx.x;
  const int t = threadIdx.x;
  size_t off = (size_t)tok * DD + t;
  float q  = q_s[off], k = k_s[off];
  float qv = (float)qvh[off], kv = (float)kvh[off];
  float sq  = block_sum_256(q * q);
  float sk  = block_sum_256(k * k);
  float svq = block_sum_256(qv * qv);
  float svk = block_sum_256(kv * kv);
  float nq = sqrtf(fmaxf(sq, EPSF));
  float nk = sqrtf(fmaxf(sk, EPSF));
  qh[off] = (f16)(q * (sinhf(nq) / nq));
  kh[off] = (f16)(k * (sinhf(nk) / nk));
  if (t == 0) {
    q0[tok] = coshf(nq);
    k0v[tok] = coshf(nk);
    q_sq[tok] = svq;
    k_sq[tok] = svk;
  }
}

// ---------------- logits: dual MFMA (A=keys, B=queries) + fast-acosh epilogue
// acc[i][j][r]: key = bk + wr*64 + i*16 + (l>>4)*4 + r (contiguous in r),
//              query = bq + wc*64 + j*16 + (l&15)  -> float4 stores along keys.
__global__ __launch_bounds__(256, 2) void logits_mfma(
    const f16* __restrict__ qh, const f16* __restrict__ kh,
    const f16* __restrict__ qvh, const f16* __restrict__ kvh,
    const float* __restrict__ q0a, const float* __restrict__ k0a,
    const float* __restrict__ qsqa, const float* __restrict__ ksqa,
    const float* __restrict__ tau, float* __restrict__ attn) {
  __shared__ __align__(16) f16 sQ[128 * 32], sK[128 * 32], sQv[128 * 32], sKv[128 * 32];
  const int tid = threadIdx.x;
  const int b = blockIdx.z;
  const int bq = blockIdx.x * 128;   // queries
  const int bk = blockIdx.y * 128;   // keys
  const size_t tb = (size_t)b * NN;
  const f16* Q  = qh  + (tb + bq) * DD;
  const f16* Kp = kh  + (tb + bk) * DD;
  const f16* Qv = qvh + (tb + bq) * DD;
  const f16* Kv = kvh + (tb + bk) * DD;
  const int w = tid >> 6, l = tid & 63;
  const int wr = w >> 1, wc = w & 1;
  f32x4 accq[4][4] = {}, accv[4][4] = {};

  for (int k0 = 0; k0 < DD; k0 += 32) {
    __syncthreads();
#pragma unroll
    for (int p = 0; p < 2; p++) {
      int u = tid + p * 256, row = u >> 2, cu = u & 3;
      size_t go = (size_t)row * DD + k0 + cu * 8;
      f16* lb = (f16*)nullptr;
      const size_t lbase = (size_t)(w * 64 + p * 256) * 8;
      (void)lb;
      gll16(Kp + go, sK  + lbase);
      gll16(Q  + go, sQ  + lbase);
      gll16(Kv + go, sKv + lbase);
      gll16(Qv + go, sQv + lbase);
    }
    __syncthreads();
    {
      f16x8 ak[4], bqf[4];
#pragma unroll
      for (int i = 0; i < 4; i++)
        ak[i] = *(const f16x8*)(sK + (wr * 64 + i * 16 + (l & 15)) * 32 + (l >> 4) * 8);
#pragma unroll
      for (int j = 0; j < 4; j++)
        bqf[j] = *(const f16x8*)(sQ + (wc * 64 + j * 16 + (l & 15)) * 32 + (l >> 4) * 8);
#pragma unroll
      for (int i = 0; i < 4; i++)
#pragma unroll
        for (int j = 0; j < 4; j++)
          accq[i][j] = mfma16(ak[i], bqf[j], accq[i][j]);
    }
    {
      f16x8 ak[4], bqf[4];
#pragma unroll
      for (int i = 0; i < 4; i++)
        ak[i] = *(const f16x8*)(sKv + (wr * 64 + i * 16 + (l & 15)) * 32 + (l >> 4) * 8);
#pragma unroll
      for (int j = 0; j < 4; j++)
        bqf[j] = *(const f16x8*)(sQv + (wc * 64 + j * 16 + (l & 15)) * 32 + (l >> 4) * 8);
#pragma unroll
      for (int i = 0; i < 4; i++)
#pragma unroll
        for (int j = 0; j < 4; j++)
          accv[i][j] = mfma16(ak[i], bqf[j], accv[i][j]);
    }
  }

  const int rl = (l >> 4) * 4, cl = l & 15;
  const float invt = 1.f / fmaxf(tau[0], 1e-3f);
  const float cc = invt * 0.4804530139182014f;   // ln2^2
  float q0r[4], qsr[4];
  float4 k0c[4], ksc[4];
#pragma unroll
  for (int j = 0; j < 4; j++) {
    const int qq = bq + wc * 64 + j * 16 + cl;
    q0r[j] = q0a[tb + qq];
    qsr[j] = qsqa[tb + qq];
  }
#pragma unroll
  for (int i = 0; i < 4; i++) {
    const int kk = bk + wr * 64 + i * 16 + rl;
    k0c[i] = *(const float4*)(k0a + tb + kk);
    ksc[i] = *(const float4*)(ksqa + tb + kk);
  }
  const size_t obase = (size_t)b * NN * NN;
#pragma unroll
  for (int j = 0; j < 4; j++) {
    const int qq = bq + wc * 64 + j * 16 + cl;
    const float q0 = q0r[j], qs = qsr[j];
#pragma unroll
    for (int i = 0; i < 4; i++) {
      const int kk = bk + wr * 64 + i * 16 + rl;
      const float* k0p = (const float*)&k0c[i];
      const float* ksp = (const float*)&ksc[i];
      float4 o;
      float* op = (float*)&o;
#pragma unroll
      for (int r = 0; r < 4; r++) {
        float xv = fmaxf(fmaf(q0, k0p[r], -accq[i][j][r]), 1.f + EPSF);
        float s = sqrtf(fmaf(xv, xv, -1.f));
        float lg = __log2f(xv + s);
        float pen = fmaxf(fmaf(-2.f, accv[i][j][r], qs + ksp[r]), 0.f);
        op[r] = fmaf(-cc * lg, lg, -pen);
      }
      *(float4*)(attn + obase + (size_t)qq * NN + kk) = o;
    }
  }
}

// ---------------- softmax over 2048, in place (fp32, d_out) ------------------
__global__ __launch_bounds__(256) void softmax_kernel(float* __restrict__ attn) {
  const size_t row = blockIdx.x;
  float4* p4 = (float4*)(attn + row * (size_t)NN);
  const int t = threadIdx.x;
  float4 a = p4[t * 2], b = p4[t * 2 + 1];
  float mx = fmaxf(fmaxf(fmaxf(a.x, a.y), fmaxf(a.z, a.w)),
                   fmaxf(fmaxf(b.x, b.y), fmaxf(b.z, b.w)));
  mx = block_max_256(mx);
  float e0 = __expf(a.x - mx), e1 = __expf(a.y - mx);
  float e2 = __expf(a.z - mx), e3 = __expf(a.w - mx);
  float e4 = __expf(b.x - mx), e5 = __expf(b.y - mx);
  float e6 = __expf(b.z - mx), e7 = __expf(b.w - mx);
  float s = ((e0 + e1) + (e2 + e3)) + ((e4 + e5) + (e6 + e7));
  s = block_sum_256(s);
  float inv = 1.f / s;
  a.x = e0 * inv; a.y = e1 * inv; a.z = e2 * inv; a.w = e3 * inv;
  b.x = e4 * inv; b.y = e5 * inv; b.z = e6 * inv; b.w = e7 * inv;
  p4[t * 2] = a;
  p4[t * 2 + 1] = b;
}

// ---------------- K7: z = exp_map0(pad(agg)) --------------------------------
__global__ __launch_bounds__(256) void zmap_kernel(
    const float* __restrict__ agg, float* __restrict__ z) {
  const int tok = blockIdx.x;
  const int t = threadIdx.x;
  float a = agg[(size_t)tok * DD + t];
  float ss = block_sum_256(a * a);
  float n = sqrtf(fmaxf(ss, EPSF));
  float sc = sinhf(n) / n;
  if (t == 0) z[(size_t)tok * DP1] = coshf(n);
  z[(size_t)tok * DP1 + 1 + t] = sc * a;
}

// ---------------- launch -----------------------------------------------------
extern "C" void kernel_launch(void* const* d_in, const int* in_sizes, int n_in,
                              void* d_out, int out_size, void* d_ws, size_t ws_size,
                              hipStream_t stream) {
  const float* x   = (const float*)d_in[0];
  const float* xv  = (const float*)d_in[1];
  const float* Wq  = (const float*)d_in[2];
  const float* bq  = (const float*)d_in[3];
  const float* Wk  = (const float*)d_in[4];
  const float* bk  = (const float*)d_in[5];
  const float* Wv  = (const float*)d_in[6];
  const float* bv  = (const float*)d_in[7];
  const float* tau = (const float*)d_in[8];
  float* out = (float*)d_out;
  char* ws = (char*)d_ws;

  const size_t TD4 = (size_t)TT * DD * 4;   // 16 MB fp32 panel
  const size_t TD2 = (size_t)TT * DD * 2;   // 8 MB f16 panel

  float* q_s32  = (float*)(ws);                       // reused as agg later
  float* k_s32  = (float*)(ws + TD4);
  f16*   qh     = (f16*)(ws + 2 * TD4);
  f16*   kh     = (f16*)(ws + 2 * TD4 + TD2);
  f16*   qvh    = (f16*)(ws + 2 * TD4 + 2 * TD2);
  f16*   kvh    = (f16*)(ws + 2 * TD4 + 3 * TD2);
  f16*   xtan_h = (f16*)(ws + 2 * TD4 + 4 * TD2);
  f16*   vel0_h = (f16*)(ws + 2 * TD4 + 5 * TD2);
  f16*   vT     = (f16*)(ws + 2 * TD4 + 6 * TD2);
  f16*   Wh     = (f16*)(ws + 2 * TD4 + 7 * TD2);
  float* q0     = (float*)(ws + 2 * TD4 + 7 * TD2 + 3 * DD * DD * 2);
  float* k0v    = q0 + TT;
  float* q_sq   = q0 + 2 * TT;
  float* k_sq   = q0 + 3 * TT;
  float* agg    = q_s32;   // alias: q_s32 dead after scale_kernel

  float* z_out    = out;
  float* attn_out = out + (size_t)TT * DP1;
  float* xtan_out = attn_out + (size_t)BB * NN * NN;

  prep_kernel<<<TT, 256, 0, stream>>>(x, xv, xtan_out, xtan_h, vel0_h);
  wcast_kernel<<<dim3(DD * DD / 256, 3), 256, 0, stream>>>(Wq, Wk, Wv, Wh);

  // fused x_tan GEMM: N = 768 = [q_s | k_s | vT]
  gemm_mfma<128, false><<<dim3(TT / 128, 768 / 128), 256, 0, stream>>>(
      xtan_h, 0, DD, Wh, 0, DD, DD,
      q_s32, k_s32, vT, bq, bk, bv, 2, 2, 1, 0);

  // fused vel GEMM: N = 512 = [q_vel | k_vel]
  gemm_mfma<128, false><<<dim3(TT / 128, 512 / 128), 256, 0, stream>>>(
      vel0_h, 0, DD, Wh, 0, DD, DD,
      qvh, kvh, nullptr, bq, bk, nullptr, 0, 0, 0, 0);

  scale_kernel<<<TT, 256, 0, stream>>>(q_s32, k_s32, qvh, kvh, qh, kh, q0, k0v, q_sq, k_sq);

  logits_mfma<<<dim3(NN / 128, NN / 128, BB), 256, 0, stream>>>(
      qh, kh, qvh, kvh, q0, k0v, q_sq, k_sq, tau, attn_out);

  softmax_kernel<<<TT, 256, 0, stream>>>(attn_out);

  // PV: agg[b,n,d] = sum_m attn[b,n,m] * vT[b,d,m] ; 64-row tiles, 512 blocks
  gemm_mfma<64, true><<<dim3(NN / 64, DD / 128, BB), 256, 0, stream>>>(
      attn_out, (size_t)NN * NN, NN, vT, (size_t)DD * NN, NN, NN,
      agg, nullptr, nullptr, nullptr, nullptr, nullptr, 2, 2, 2,
      (size_t)NN * DD);

  zmap_kernel<<<TT, 256, 0, stream>>>(agg, z_out);
}

// Round 4
// 262.245 us; speedup vs baseline: 4.3507x; 1.0450x over previous
//
#include <hip/hip_runtime.h>
#include <math.h>

#define BB 8
#define NN 2048
#define DD 256
#define TT (BB*NN)      // 16384 tokens
#define DP1 257
#define EPSF 1e-6f

typedef _Float16 f16;
typedef __attribute__((ext_vector_type(8))) _Float16 f16x8;
typedef __attribute__((ext_vector_type(4))) float f32x4;

__device__ __forceinline__ f32x4 mfma16(f16x8 a, f16x8 b, f32x4 c) {
  return __builtin_amdgcn_mfma_f32_16x16x32_f16(a, b, c, 0, 0, 0);
}
// async global->LDS, 16B/lane; dest = wave-uniform base + lane*16.
__device__ __forceinline__ void gll16(const f16* g, f16* l) {
  __builtin_amdgcn_global_load_lds(
      (const __attribute__((address_space(1))) void*)g,
      (__attribute__((address_space(3))) void*)l, 16, 0, 0);
}

// ---------------- block-wide sum (256 threads) ----------------
__device__ __forceinline__ float block_sum_256(float v) {
  __shared__ float s[256];
  int t = threadIdx.x;
  s[t] = v;
  __syncthreads();
#pragma unroll
  for (int st = 128; st > 0; st >>= 1) {
    if (t < st) s[t] += s[t + st];
    __syncthreads();
  }
  float r = s[0];
  __syncthreads();
  return r;
}

// ---------------- K1: x_tan fp32 (output) + f16 copies ----------------------
__global__ __launch_bounds__(256) void prep_kernel(
    const float* __restrict__ x, const float* __restrict__ xv,
    float* __restrict__ xtan, f16* __restrict__ xtan_h, f16* __restrict__ vel0_h) {
  const int tok = blockIdx.x;
  const int t = threadIdx.x;
  const float* xr = x  + (size_t)tok * DP1;
  const float* vr = xv + (size_t)tok * DP1;
  float x0 = xr[0];
  float sp = xr[1 + t];
  float ss = block_sum_256(sp * sp);
  float n  = sqrtf(fmaxf(ss, EPSF));
  float dd = acoshf(fmaxf(x0, 1.f + EPSF));
  float xt = (dd / n) * sp;
  xtan[(size_t)tok * DD + t] = xt;
  xtan_h[(size_t)tok * DD + t] = (f16)xt;
  float coef = -vr[0] / (1.f + x0);
  vel0_h[(size_t)tok * DD + t] = (f16)(vr[1 + t] + coef * sp);
}

// ---------------- weight cast fp32 -> f16, Wh = [Wq;Wk;Wv] ------------------
__global__ __launch_bounds__(256) void wcast_kernel(
    const float* __restrict__ Wq, const float* __restrict__ Wk,
    const float* __restrict__ Wv, f16* __restrict__ Wh) {
  const int m = blockIdx.y;
  const int i = blockIdx.x * 256 + threadIdx.x;
  const float* W = (m == 0) ? Wq : ((m == 1) ? Wk : Wv);
  Wh[(size_t)m * DD * DD + i] = (f16)W[i];
}

// ---------------- MFMA GEMM, 128x128 tile, 2-phase dbuf, K=256 ---------------
// N segmented in 256-col chunks; per-seg out ptr / bias / type:
//   type 0 = f16 row-major (ldc=256), 1 = f16 transposed per-batch [d][m]
__global__ __launch_bounds__(256, 2) void gemm_mfma(
    const f16* __restrict__ A, const f16* __restrict__ B,
    void* o0, void* o1, void* o2,
    const float* b0, const float* b1, const float* b2,
    int t0, int t1, int t2) {
  __shared__ __align__(16) f16 sA[2 * 4096];
  __shared__ __align__(16) f16 sB[2 * 4096];
  const int tid = threadIdx.x;
  const int bm = blockIdx.x * 128;
  const int bn = blockIdx.y * 128;
  const int w = tid >> 6, l = tid & 63;
  const int wr = w >> 1, wc = w & 1;
  f32x4 acc[4][4] = {};
  const f16* Ab = A + (size_t)bm * DD;
  const f16* Bb = B + (size_t)bn * DD;

  for (int kt = -1; kt < 8; ++kt) {
    const int nx = kt + 1;
    if (nx < 8) {
      const int half = nx & 1, k0 = nx * 32;
#pragma unroll
      for (int p = 0; p < 2; p++) {
        int u = tid + p * 256, row = u >> 2, cu = u & 3;
        size_t go = (size_t)row * DD + k0 + cu * 8;
        size_t lb = (size_t)half * 4096 + (size_t)(w * 64 + p * 256) * 8;
        gll16(Ab + go, sA + lb);
        gll16(Bb + go, sB + lb);
      }
    }
    if (kt >= 0) {
      const int cur = kt & 1;
      f16x8 af[4], bf[4];
#pragma unroll
      for (int i = 0; i < 4; i++)
        af[i] = *(const f16x8*)(sA + cur * 4096 + (wr * 64 + i * 16 + (l & 15)) * 32 + (l >> 4) * 8);
#pragma unroll
      for (int j = 0; j < 4; j++)
        bf[j] = *(const f16x8*)(sB + cur * 4096 + (wc * 64 + j * 16 + (l & 15)) * 32 + (l >> 4) * 8);
#pragma unroll
      for (int i = 0; i < 4; i++)
#pragma unroll
        for (int j = 0; j < 4; j++)
          acc[i][j] = mfma16(af[i], bf[j], acc[i][j]);
    }
    __syncthreads();
  }

  // epilogue: C/D layout col=lane&15, row=(lane>>4)*4+r
  const int seg = bn >> 8;
  void* optr = (seg == 0) ? o0 : ((seg == 1) ? o1 : o2);
  const float* bias = (seg == 0) ? b0 : ((seg == 1) ? b1 : b2);
  const int ot = (seg == 0) ? t0 : ((seg == 1) ? t1 : t2);
  const int rl = (l >> 4) * 4, cl = l & 15;
#pragma unroll
  for (int i = 0; i < 4; i++) {
#pragma unroll
    for (int j = 0; j < 4; j++) {
      const int col = (bn & 255) + wc * 64 + j * 16 + cl;
      const float bv = bias ? bias[col] : 0.f;
      const int row0 = bm + wr * 64 + i * 16 + rl;
      if (ot == 0) {
        f16* C = (f16*)optr;
#pragma unroll
        for (int r = 0; r < 4; r++)
          C[(size_t)(row0 + r) * DD + col] = (f16)(acc[i][j][r] + bv);
      } else {
        __align__(8) f16 tmp[4];
#pragma unroll
        for (int r = 0; r < 4; r++) tmp[r] = (f16)(acc[i][j][r] + bv);
        f16* dst = (f16*)optr + ((size_t)((row0 >> 11) * DD + col)) * NN + (row0 & (NN - 1));
        *(uint2*)dst = *(const uint2*)tmp;
      }
    }
  }
}

// ---------------- scale: in-place f16 q/k scaling + scalars ------------------
__global__ __launch_bounds__(256) void scale_kernel(
    f16* __restrict__ qh, f16* __restrict__ kh,
    const f16* __restrict__ qvh, const f16* __restrict__ kvh,
    float* __restrict__ q0, float* __restrict__ k0v,
    float* __restrict__ q_sq, float* __restrict__ k_sq) {
  const int tok = blockIdx.x;
  const int t = threadIdx.x;
  size_t off = (size_t)tok * DD + t;
  float q  = (float)qh[off], k = (float)kh[off];
  float qv = (float)qvh[off], kv = (float)kvh[off];
  float sq  = block_sum_256(q * q);
  float sk  = block_sum_256(k * k);
  float svq = block_sum_256(qv * qv);
  float svk = block_sum_256(kv * kv);
  float nq = sqrtf(fmaxf(sq, EPSF));
  float nk = sqrtf(fmaxf(sk, EPSF));
  qh[off] = (f16)(q * (sinhf(nq) / nq));
  kh[off] = (f16)(k * (sinhf(nk) / nk));
  if (t == 0) {
    q0[tok] = coshf(nq);
    k0v[tok] = coshf(nk);
    q_sq[tok] = svq;
    k_sq[tok] = svk;
  }
}

// ---------------- logits: dual MFMA, 2-phase dbuf, fused exp-rowsum ----------
// acc[i][j][r]: key = bk + wr*64 + i*16 + (l>>4)*4 + r, query = bq + wc*64 + j*16 + (l&15)
__global__ __launch_bounds__(256, 2) void logits_mfma(
    const f16* __restrict__ qh, const f16* __restrict__ kh,
    const f16* __restrict__ qvh, const f16* __restrict__ kvh,
    const float* __restrict__ q0a, const float* __restrict__ k0a,
    const float* __restrict__ qsqa, const float* __restrict__ ksqa,
    const float* __restrict__ tau, float* __restrict__ attn,
    float* __restrict__ psum) {
  __shared__ __align__(16) f16 sQ[2*4096], sK[2*4096], sQv[2*4096], sKv[2*4096];
  const int tid = threadIdx.x;
  const int b = blockIdx.z;
  const int bq = blockIdx.x * 128;   // queries
  const int bk = blockIdx.y * 128;   // keys
  const size_t tb = (size_t)b * NN;
  const f16* Q  = qh  + (tb + bq) * DD;
  const f16* Kp = kh  + (tb + bk) * DD;
  const f16* Qv = qvh + (tb + bq) * DD;
  const f16* Kv = kvh + (tb + bk) * DD;
  const int w = tid >> 6, l = tid & 63;
  const int wr = w >> 1, wc = w & 1;
  f32x4 accq[4][4] = {}, accv[4][4] = {};

  for (int kt = -1; kt < 8; ++kt) {
    const int nx = kt + 1;
    if (nx < 8) {
      const int half = nx & 1, k0 = nx * 32;
#pragma unroll
      for (int p = 0; p < 2; p++) {
        int u = tid + p * 256, row = u >> 2, cu = u & 3;
        size_t go = (size_t)row * DD + k0 + cu * 8;
        size_t lb = (size_t)half * 4096 + (size_t)(w * 64 + p * 256) * 8;
        gll16(Kp + go, sK  + lb);
        gll16(Q  + go, sQ  + lb);
        gll16(Kv + go, sKv + lb);
        gll16(Qv + go, sQv + lb);
      }
    }
    if (kt >= 0) {
      const int cur = kt & 1;
      const int co = cur * 4096;
      {
        f16x8 ak[4], bqf[4];
#pragma unroll
        for (int i = 0; i < 4; i++)
          ak[i] = *(const f16x8*)(sK + co + (wr * 64 + i * 16 + (l & 15)) * 32 + (l >> 4) * 8);
#pragma unroll
        for (int j = 0; j < 4; j++)
          bqf[j] = *(const f16x8*)(sQ + co + (wc * 64 + j * 16 + (l & 15)) * 32 + (l >> 4) * 8);
#pragma unroll
        for (int i = 0; i < 4; i++)
#pragma unroll
          for (int j = 0; j < 4; j++)
            accq[i][j] = mfma16(ak[i], bqf[j], accq[i][j]);
      }
      {
        f16x8 ak[4], bqf[4];
#pragma unroll
        for (int i = 0; i < 4; i++)
          ak[i] = *(const f16x8*)(sKv + co + (wr * 64 + i * 16 + (l & 15)) * 32 + (l >> 4) * 8);
#pragma unroll
        for (int j = 0; j < 4; j++)
          bqf[j] = *(const f16x8*)(sQv + co + (wc * 64 + j * 16 + (l & 15)) * 32 + (l >> 4) * 8);
#pragma unroll
        for (int i = 0; i < 4; i++)
#pragma unroll
          for (int j = 0; j < 4; j++)
            accv[i][j] = mfma16(ak[i], bqf[j], accv[i][j]);
      }
    }
    __syncthreads();
  }

  const int rl = (l >> 4) * 4, cl = l & 15;
  const float invt = 1.f / fmaxf(tau[0], 1e-3f);
  const float cc = invt * 0.4804530139182014f;   // ln2^2
  float q0r[4], qsr[4];
  float4 k0c[4], ksc[4];
#pragma unroll
  for (int j = 0; j < 4; j++) {
    const int qq = bq + wc * 64 + j * 16 + cl;
    q0r[j] = q0a[tb + qq];
    qsr[j] = qsqa[tb + qq];
  }
#pragma unroll
  for (int i = 0; i < 4; i++) {
    const int kk = bk + wr * 64 + i * 16 + rl;
    k0c[i] = *(const float4*)(k0a + tb + kk);
    ksc[i] = *(const float4*)(ksqa + tb + kk);
  }
  const size_t obase = (size_t)b * NN * NN;
#pragma unroll
  for (int j = 0; j < 4; j++) {
    const int qq = bq + wc * 64 + j * 16 + cl;
    const float q0 = q0r[j], qs = qsr[j];
    float es = 0.f;
#pragma unroll
    for (int i = 0; i < 4; i++) {
      const int kk = bk + wr * 64 + i * 16 + rl;
      const float* k0p = (const float*)&k0c[i];
      const float* ksp = (const float*)&ksc[i];
      float4 o;
      float* op = (float*)&o;
#pragma unroll
      for (int r = 0; r < 4; r++) {
        float xv = fmaxf(fmaf(q0, k0p[r], -accq[i][j][r]), 1.f + EPSF);
        float s = sqrtf(fmaf(xv, xv, -1.f));
        float lg = __log2f(xv + s);
        float pen = fmaxf(fmaf(-2.f, accv[i][j][r], qs + ksp[r]), 0.f);
        float lo = fmaf(-cc * lg, lg, -pen);
        op[r] = lo;
        es += __expf(lo);
      }
      *(float4*)(attn + obase + (size_t)qq * NN + kk) = o;
    }
    // reduce es over the 4 lanes sharing this query (l ^ 16, l ^ 32)
    es += __shfl_xor(es, 16);
    es += __shfl_xor(es, 32);
    if ((l >> 4) == 0)
      psum[((size_t)(b * 16 + blockIdx.y) * 2 + wr) * NN + qq] = es;
  }
}

// ---------------- fused softmax + PV + exp-map (z) ---------------------------
// block: 32 rows of one batch, all 256 d. Reads raw logits from attn region,
// writes normalized attn in place, agg in regs, z at the end.
__global__ __launch_bounds__(256, 2) void pv_fused(
    const float* __restrict__ psum, const f16* __restrict__ vT,
    float* __restrict__ attn, float* __restrict__ z) {
  __shared__ __align__(16) f16 sP[2][32 * 32];
  __shared__ __align__(16) f16 sV[2][256 * 32];
  __shared__ float invs_l[32];
  __shared__ float zsum[4][32];
  __shared__ float zsc[32];
  const int tid = threadIdx.x;
  const int b = blockIdx.y;
  const int row0 = blockIdx.x * 32;
  const int w = tid >> 6, l = tid & 63;
  float* slab = attn + ((size_t)b * NN + row0) * NN;   // logits in / attn out
  const f16* Vb = vT + (size_t)b * DD * NN;

  if (tid < 32) {
    float s = 0.f;
#pragma unroll 4
    for (int p = 0; p < 32; p++) s += psum[((size_t)b * 32 + p) * NN + row0 + tid];
    invs_l[tid] = 1.f / s;
  }
  __syncthreads();
  const int prow = tid >> 3, pm4 = tid & 7;
  const float myinv = invs_l[prow];
  f32x4 acc[2][4] = {};

  for (int t = -1; t < 64; ++t) {
    const int nx = t + 1;
    float4 pl;
    if (nx < 64) {
      const int m0 = nx * 32;
#pragma unroll
      for (int p = 0; p < 4; p++) {
        int u = tid + p * 256, d = u >> 2, mq = u & 3;
        gll16(Vb + (size_t)d * NN + m0 + mq * 8,
              &sV[nx & 1][0] + (size_t)(w * 64 + p * 256) * 8);
      }
      pl = *(const float4*)(slab + (size_t)prow * NN + m0 + pm4 * 4);
    }
    if (t >= 0) {
      const int cur = t & 1;
      f16x8 af[2], bf[4];
#pragma unroll
      for (int i = 0; i < 2; i++)
        af[i] = *(const f16x8*)(&sP[cur][(i * 16 + (l & 15)) * 32 + (l >> 4) * 8]);
#pragma unroll
      for (int j = 0; j < 4; j++)
        bf[j] = *(const f16x8*)(&sV[cur][(w * 64 + j * 16 + (l & 15)) * 32 + (l >> 4) * 8]);
#pragma unroll
      for (int i = 0; i < 2; i++)
#pragma unroll
        for (int j = 0; j < 4; j++)
          acc[i][j] = mfma16(af[i], bf[j], acc[i][j]);
    }
    if (nx < 64) {
      const int m0 = nx * 32;
      float e0 = __expf(pl.x) * myinv, e1 = __expf(pl.y) * myinv;
      float e2 = __expf(pl.z) * myinv, e3 = __expf(pl.w) * myinv;
      float4 ov = {e0, e1, e2, e3};
      *(float4*)(slab + (size_t)prow * NN + m0 + pm4 * 4) = ov;
      __align__(8) f16 tmp[4] = {(f16)e0, (f16)e1, (f16)e2, (f16)e3};
      *(uint2*)(&sP[nx & 1][prow * 32 + pm4 * 4]) = *(const uint2*)tmp;
    }
    __syncthreads();
  }

  // z = exp_map0(pad(agg)); rows fully within this block.
  const int rl4 = (l >> 4) * 4, cl = l & 15;
  float s2[2][4];
#pragma unroll
  for (int i = 0; i < 2; i++)
#pragma unroll
    for (int r = 0; r < 4; r++) {
      float s = 0.f;
#pragma unroll
      for (int j = 0; j < 4; j++) s = fmaf(acc[i][j][r], acc[i][j][r], s);
#pragma unroll
      for (int m = 1; m < 16; m <<= 1) s += __shfl_xor(s, m);
      s2[i][r] = s;
    }
  if (cl == 0) {
#pragma unroll
    for (int i = 0; i < 2; i++)
#pragma unroll
      for (int r = 0; r < 4; r++)
        zsum[w][i * 16 + rl4 + r] = s2[i][r];
  }
  __syncthreads();
  if (tid < 32) {
    float n2 = zsum[0][tid] + zsum[1][tid] + zsum[2][tid] + zsum[3][tid];
    float nn = sqrtf(fmaxf(n2, EPSF));
    zsc[tid] = sinhf(nn) / nn;
    z[(size_t)(b * NN + row0 + tid) * DP1] = coshf(nn);
  }
  __syncthreads();
#pragma unroll
  for (int i = 0; i < 2; i++)
#pragma unroll
    for (int r = 0; r < 4; r++) {
      const int row = i * 16 + rl4 + r;
      const float sc = zsc[row];
      const size_t zb = (size_t)(b * NN + row0 + row) * DP1 + 1;
#pragma unroll
      for (int j = 0; j < 4; j++)
        z[zb + w * 64 + j * 16 + cl] = acc[i][j][r] * sc;
    }
}

// ---------------- launch -----------------------------------------------------
extern "C" void kernel_launch(void* const* d_in, const int* in_sizes, int n_in,
                              void* d_out, int out_size, void* d_ws, size_t ws_size,
                              hipStream_t stream) {
  const float* x   = (const float*)d_in[0];
  const float* xv  = (const float*)d_in[1];
  const float* Wq  = (const float*)d_in[2];
  const float* bq  = (const float*)d_in[3];
  const float* Wk  = (const float*)d_in[4];
  const float* bk  = (const float*)d_in[5];
  const float* Wv  = (const float*)d_in[6];
  const float* bv  = (const float*)d_in[7];
  const float* tau = (const float*)d_in[8];
  float* out = (float*)d_out;
  char* ws = (char*)d_ws;

  const size_t TD2 = (size_t)TT * DD * 2;   // 8 MB f16 panel

  f16*   qh     = (f16*)(ws);               // GEMM1 out, scaled in place
  f16*   kh     = (f16*)(ws + TD2);
  f16*   qvh    = (f16*)(ws + 2 * TD2);
  f16*   kvh    = (f16*)(ws + 3 * TD2);
  f16*   vT     = (f16*)(ws + 4 * TD2);
  f16*   xtan_h = (f16*)(ws + 5 * TD2);
  f16*   vel0_h = (f16*)(ws + 6 * TD2);
  f16*   Wh     = (f16*)(ws + 7 * TD2);
  float* psum   = (float*)(ws + 7 * TD2 + 3 * DD * DD * 2);        // [8][32][2048]
  float* q0     = psum + (size_t)BB * 32 * NN;
  float* k0v    = q0 + TT;
  float* q_sq   = q0 + 2 * TT;
  float* k_sq   = q0 + 3 * TT;

  float* z_out    = out;
  float* attn_out = out + (size_t)TT * DP1;
  float* xtan_out = attn_out + (size_t)BB * NN * NN;

  prep_kernel<<<TT, 256, 0, stream>>>(x, xv, xtan_out, xtan_h, vel0_h);
  wcast_kernel<<<dim3(DD * DD / 256, 3), 256, 0, stream>>>(Wq, Wk, Wv, Wh);

  // fused x_tan GEMM: N = 768 = [q_s | k_s | vT]
  gemm_mfma<<<dim3(TT / 128, 6), 256, 0, stream>>>(
      xtan_h, Wh, qh, kh, vT, bq, bk, bv, 0, 0, 1);

  // fused vel GEMM: N = 512 = [q_vel | k_vel]
  gemm_mfma<<<dim3(TT / 128, 4), 256, 0, stream>>>(
      vel0_h, Wh, qvh, kvh, nullptr, bq, bk, nullptr, 0, 0, 0);

  scale_kernel<<<TT, 256, 0, stream>>>(qh, kh, qvh, kvh, q0, k0v, q_sq, k_sq);

  logits_mfma<<<dim3(NN / 128, NN / 128, BB), 256, 0, stream>>>(
      qh, kh, qvh, kvh, q0, k0v, q_sq, k_sq, tau, attn_out, psum);

  pv_fused<<<dim3(NN / 32, BB), 256, 0, stream>>>(psum, vT, attn_out, z_out);
}

// Round 5
// 258.580 us; speedup vs baseline: 4.4124x; 1.0142x over previous
//
#include <hip/hip_runtime.h>
#include <math.h>

#define BB 8
#define NN 2048
#define DD 256
#define TT (BB*NN)      // 16384 tokens
#define DP1 257
#define EPSF 1e-6f

typedef _Float16 f16;
typedef __attribute__((ext_vector_type(8))) _Float16 f16x8;
typedef __attribute__((ext_vector_type(4))) float f32x4;

#define BAR() asm volatile("s_barrier" ::: "memory")
#define WAIT_VM(N) asm volatile("s_waitcnt vmcnt(" #N ")" ::: "memory")

__device__ __forceinline__ f32x4 mfma16(f16x8 a, f16x8 b, f32x4 c) {
  return __builtin_amdgcn_mfma_f32_16x16x32_f16(a, b, c, 0, 0, 0);
}
// async global->LDS, 16B/lane; dest = wave-uniform base + lane*16.
__device__ __forceinline__ void gll16(const f16* g, f16* l) {
  __builtin_amdgcn_global_load_lds(
      (const __attribute__((address_space(1))) void*)g,
      (__attribute__((address_space(3))) void*)l, 16, 0, 0);
}

// LDS XOR-swizzle (both-sides, rule #21): linear slot u=(row,s) holds global
// quarter q = s ^ ((row>>1)&3); fragment reads use the same XOR.
// Spreads the 64B-row-stride fragment reads from 8-way conflict to 2-way.

// ---------------- block-wide sum (256 threads) ----------------
__device__ __forceinline__ float block_sum_256(float v) {
  __shared__ float s[256];
  int t = threadIdx.x;
  s[t] = v;
  __syncthreads();
#pragma unroll
  for (int st = 128; st > 0; st >>= 1) {
    if (t < st) s[t] += s[t + st];
    __syncthreads();
  }
  float r = s[0];
  __syncthreads();
  return r;
}

// ---------------- K1: x_tan fp32 (output) + f16 copies ----------------------
__global__ __launch_bounds__(256) void prep_kernel(
    const float* __restrict__ x, const float* __restrict__ xv,
    float* __restrict__ xtan, f16* __restrict__ xtan_h, f16* __restrict__ vel0_h) {
  const int tok = blockIdx.x;
  const int t = threadIdx.x;
  const float* xr = x  + (size_t)tok * DP1;
  const float* vr = xv + (size_t)tok * DP1;
  float x0 = xr[0];
  float sp = xr[1 + t];
  float ss = block_sum_256(sp * sp);
  float n  = sqrtf(fmaxf(ss, EPSF));
  float dd = acoshf(fmaxf(x0, 1.f + EPSF));
  float xt = (dd / n) * sp;
  xtan[(size_t)tok * DD + t] = xt;
  xtan_h[(size_t)tok * DD + t] = (f16)xt;
  float coef = -vr[0] / (1.f + x0);
  vel0_h[(size_t)tok * DD + t] = (f16)(vr[1 + t] + coef * sp);
}

// ---------------- weight cast fp32 -> f16, Wh = [Wq;Wk;Wv] ------------------
__global__ __launch_bounds__(256) void wcast_kernel(
    const float* __restrict__ Wq, const float* __restrict__ Wk,
    const float* __restrict__ Wv, f16* __restrict__ Wh) {
  const int m = blockIdx.y;
  const int i = blockIdx.x * 256 + threadIdx.x;
  const float* W = (m == 0) ? Wq : ((m == 1) ? Wk : Wv);
  Wh[(size_t)m * DD * DD + i] = (f16)W[i];
}

// ---------------- MFMA GEMM, 128x128 tile, counted-vmcnt pipeline ------------
// N segmented in 256-col chunks; per-seg out ptr / bias / type:
//   type 0 = f16 row-major (ldc=256), 1 = f16 transposed per-batch [d][m]
__global__ __launch_bounds__(256, 2) void gemm_mfma(
    const f16* __restrict__ A, const f16* __restrict__ B,
    void* o0, void* o1, void* o2,
    const float* b0, const float* b1, const float* b2,
    int t0, int t1, int t2) {
  __shared__ __align__(16) f16 sA[2 * 4096];
  __shared__ __align__(16) f16 sB[2 * 4096];
  const int tid = threadIdx.x;
  const int bm = blockIdx.x * 128;
  const int bn = blockIdx.y * 128;
  const int w = tid >> 6, l = tid & 63;
  const int wr = w >> 1, wc = w & 1;
  f32x4 acc[4][4] = {};
  const f16* Ab = A + (size_t)bm * DD;
  const f16* Bb = B + (size_t)bn * DD;

  auto stage = [&](int nx) {
    const int half = nx & 1, k0 = nx * 32;
#pragma unroll
    for (int p = 0; p < 2; p++) {
      int u = tid + p * 256;
      int row = u >> 2;
      int q = (u & 3) ^ ((u >> 3) & 3);
      size_t go = (size_t)row * DD + k0 + q * 8;
      size_t lb = (size_t)half * 4096 + (size_t)(w * 64 + p * 256) * 8;
      gll16(Ab + go, sA + lb);
      gll16(Bb + go, sB + lb);
    }
  };

  stage(0);
  const int fq = ((l >> 4) ^ ((l >> 1) & 3)) * 8;
  for (int kt = 0; kt < 8; ++kt) {
    if (kt < 7) { stage(kt + 1); WAIT_VM(4); }
    else        { WAIT_VM(0); }
    BAR();
    const int co = (kt & 1) * 4096;
    f16x8 af[4], bf[4];
#pragma unroll
    for (int i = 0; i < 4; i++)
      af[i] = *(const f16x8*)(sA + co + (wr * 64 + i * 16 + (l & 15)) * 32 + fq);
#pragma unroll
    for (int j = 0; j < 4; j++)
      bf[j] = *(const f16x8*)(sB + co + (wc * 64 + j * 16 + (l & 15)) * 32 + fq);
#pragma unroll
    for (int i = 0; i < 4; i++)
#pragma unroll
      for (int j = 0; j < 4; j++)
        acc[i][j] = mfma16(af[i], bf[j], acc[i][j]);
    BAR();
  }

  // epilogue: C/D layout col=lane&15, row=(lane>>4)*4+r
  const int seg = bn >> 8;
  void* optr = (seg == 0) ? o0 : ((seg == 1) ? o1 : o2);
  const float* bias = (seg == 0) ? b0 : ((seg == 1) ? b1 : b2);
  const int ot = (seg == 0) ? t0 : ((seg == 1) ? t1 : t2);
  const int rl = (l >> 4) * 4, cl = l & 15;
#pragma unroll
  for (int i = 0; i < 4; i++) {
#pragma unroll
    for (int j = 0; j < 4; j++) {
      const int col = (bn & 255) + wc * 64 + j * 16 + cl;
      const float bv = bias ? bias[col] : 0.f;
      const int row0 = bm + wr * 64 + i * 16 + rl;
      if (ot == 0) {
        f16* C = (f16*)optr;
#pragma unroll
        for (int r = 0; r < 4; r++)
          C[(size_t)(row0 + r) * DD + col] = (f16)(acc[i][j][r] + bv);
      } else {
        __align__(8) f16 tmp[4];
#pragma unroll
        for (int r = 0; r < 4; r++) tmp[r] = (f16)(acc[i][j][r] + bv);
        f16* dst = (f16*)optr + ((size_t)((row0 >> 11) * DD + col)) * NN + (row0 & (NN - 1));
        *(uint2*)dst = *(const uint2*)tmp;
      }
    }
  }
}

// ---------------- scale: in-place f16 q/k scaling + scalars ------------------
__global__ __launch_bounds__(256) void scale_kernel(
    f16* __restrict__ qh, f16* __restrict__ kh,
    const f16* __restrict__ qvh, const f16* __restrict__ kvh,
    float* __restrict__ q0, float* __restrict__ k0v,
    float* __restrict__ q_sq, float* __restrict__ k_sq) {
  const int tok = blockIdx.x;
  const int t = threadIdx.x;
  size_t off = (size_t)tok * DD + t;
  float q  = (float)qh[off], k = (float)kh[off];
  float qv = (float)qvh[off], kv = (float)kvh[off];
  float sq  = block_sum_256(q * q);
  float sk  = block_sum_256(k * k);
  float svq = block_sum_256(qv * qv);
  float svk = block_sum_256(kv * kv);
  float nq = sqrtf(fmaxf(sq, EPSF));
  float nk = sqrtf(fmaxf(sk, EPSF));
  qh[off] = (f16)(q * (sinhf(nq) / nq));
  kh[off] = (f16)(k * (sinhf(nk) / nk));
  if (t == 0) {
    q0[tok] = coshf(nq);
    k0v[tok] = coshf(nk);
    q_sq[tok] = svq;
    k_sq[tok] = svk;
  }
}

// ---------------- logits: dual MFMA, counted-vmcnt pipeline, fused rowsum ----
// 1D grid 2048: batch = bid&7 (XCD-local), bq = ((bid>>3)&15)*128, bk = (bid>>7)*128
__global__ __launch_bounds__(256, 2) void logits_mfma(
    const f16* __restrict__ qh, const f16* __restrict__ kh,
    const f16* __restrict__ qvh, const f16* __restrict__ kvh,
    const float* __restrict__ q0a, const float* __restrict__ k0a,
    const float* __restrict__ qsqa, const float* __restrict__ ksqa,
    const float* __restrict__ tau, float* __restrict__ attn,
    float* __restrict__ psum) {
  __shared__ __align__(16) f16 sQ[2*4096], sK[2*4096], sQv[2*4096], sKv[2*4096];
  const int tid = threadIdx.x;
  const int bid = blockIdx.x;
  const int b = bid & 7;
  const int bq = ((bid >> 3) & 15) * 128;   // queries
  const int kti = bid >> 7;                 // key-tile index
  const int bk = kti * 128;                 // keys
  const size_t tb = (size_t)b * NN;
  const f16* Q  = qh  + (tb + bq) * DD;
  const f16* Kp = kh  + (tb + bk) * DD;
  const f16* Qv = qvh + (tb + bq) * DD;
  const f16* Kv = kvh + (tb + bk) * DD;
  const int w = tid >> 6, l = tid & 63;
  const int wr = w >> 1, wc = w & 1;
  f32x4 accq[4][4] = {}, accv[4][4] = {};

  auto stage = [&](int nx) {
    const int half = nx & 1, k0 = nx * 32;
#pragma unroll
    for (int p = 0; p < 2; p++) {
      int u = tid + p * 256;
      int row = u >> 2;
      int q = (u & 3) ^ ((u >> 3) & 3);
      size_t go = (size_t)row * DD + k0 + q * 8;
      size_t lb = (size_t)half * 4096 + (size_t)(w * 64 + p * 256) * 8;
      gll16(Kp + go, sK  + lb);
      gll16(Q  + go, sQ  + lb);
      gll16(Kv + go, sKv + lb);
      gll16(Qv + go, sQv + lb);
    }
  };

  stage(0);
  const int fq = ((l >> 4) ^ ((l >> 1) & 3)) * 8;
  for (int kt = 0; kt < 8; ++kt) {
    if (kt < 7) { stage(kt + 1); WAIT_VM(8); }
    else        { WAIT_VM(0); }
    BAR();
    const int co = (kt & 1) * 4096;
    {
      f16x8 ak[4], bqf[4];
#pragma unroll
      for (int i = 0; i < 4; i++)
        ak[i] = *(const f16x8*)(sK + co + (wr * 64 + i * 16 + (l & 15)) * 32 + fq);
#pragma unroll
      for (int j = 0; j < 4; j++)
        bqf[j] = *(const f16x8*)(sQ + co + (wc * 64 + j * 16 + (l & 15)) * 32 + fq);
#pragma unroll
      for (int i = 0; i < 4; i++)
#pragma unroll
        for (int j = 0; j < 4; j++)
          accq[i][j] = mfma16(ak[i], bqf[j], accq[i][j]);
    }
    {
      f16x8 ak[4], bqf[4];
#pragma unroll
      for (int i = 0; i < 4; i++)
        ak[i] = *(const f16x8*)(sKv + co + (wr * 64 + i * 16 + (l & 15)) * 32 + fq);
#pragma unroll
      for (int j = 0; j < 4; j++)
        bqf[j] = *(const f16x8*)(sQv + co + (wc * 64 + j * 16 + (l & 15)) * 32 + fq);
#pragma unroll
      for (int i = 0; i < 4; i++)
#pragma unroll
        for (int j = 0; j < 4; j++)
          accv[i][j] = mfma16(ak[i], bqf[j], accv[i][j]);
    }
    BAR();
  }

  const int rl = (l >> 4) * 4, cl = l & 15;
  const float invt = 1.f / fmaxf(tau[0], 1e-3f);
  const float cc = invt * 0.4804530139182014f;   // ln2^2
  float q0r[4], qsr[4];
  float4 k0c[4], ksc[4];
#pragma unroll
  for (int j = 0; j < 4; j++) {
    const int qq = bq + wc * 64 + j * 16 + cl;
    q0r[j] = q0a[tb + qq];
    qsr[j] = qsqa[tb + qq];
  }
#pragma unroll
  for (int i = 0; i < 4; i++) {
    const int kk = bk + wr * 64 + i * 16 + rl;
    k0c[i] = *(const float4*)(k0a + tb + kk);
    ksc[i] = *(const float4*)(ksqa + tb + kk);
  }
  const size_t obase = (size_t)b * NN * NN;
#pragma unroll
  for (int j = 0; j < 4; j++) {
    const int qq = bq + wc * 64 + j * 16 + cl;
    const float q0 = q0r[j], qs = qsr[j];
    float es = 0.f;
#pragma unroll
    for (int i = 0; i < 4; i++) {
      const int kk = bk + wr * 64 + i * 16 + rl;
      const float* k0p = (const float*)&k0c[i];
      const float* ksp = (const float*)&ksc[i];
      float4 o;
      float* op = (float*)&o;
#pragma unroll
      for (int r = 0; r < 4; r++) {
        float xv = fmaxf(fmaf(q0, k0p[r], -accq[i][j][r]), 1.f + EPSF);
        float s = sqrtf(fmaf(xv, xv, -1.f));
        float lg = __log2f(xv + s);
        float pen = fmaxf(fmaf(-2.f, accv[i][j][r], qs + ksp[r]), 0.f);
        float lo = fmaf(-cc * lg, lg, -pen);
        op[r] = lo;
        es += __expf(lo);
      }
      *(float4*)(attn + obase + (size_t)qq * NN + kk) = o;
    }
    es += __shfl_xor(es, 16);
    es += __shfl_xor(es, 32);
    if ((l >> 4) == 0)
      psum[((size_t)(b * 16 + kti) * 2 + wr) * NN + qq] = es;
  }
}

// ---------------- fused softmax + PV + exp-map (z) ---------------------------
// 1D grid 512: batch = bid&7 (XCD-local), row0 = (bid>>3)*32.
__global__ __launch_bounds__(256, 2) void pv_fused(
    const float* __restrict__ psum, const f16* __restrict__ vT,
    float* __restrict__ attn, float* __restrict__ z) {
  __shared__ __align__(16) f16 sP[2][32 * 32];
  __shared__ __align__(16) f16 sV[2][256 * 32];
  __shared__ float invs_l[32];
  __shared__ float zsum[4][32];
  __shared__ float zsc[32];
  const int tid = threadIdx.x;
  const int bid = blockIdx.x;
  const int b = bid & 7;
  const int row0 = (bid >> 3) * 32;
  const int w = tid >> 6, l = tid & 63;
  float* slab = attn + ((size_t)b * NN + row0) * NN;   // logits in / attn out
  const f16* Vb = vT + (size_t)b * DD * NN;

  if (tid < 32) {
    float s = 0.f;
#pragma unroll 4
    for (int p = 0; p < 32; p++) s += psum[((size_t)b * 32 + p) * NN + row0 + tid];
    invs_l[tid] = 1.f / s;
  }
  __syncthreads();
  const int prow = tid >> 3, pm4 = tid & 7;
  const float myinv = invs_l[prow];
  const int fq = ((l >> 4) ^ ((l >> 1) & 3)) * 8;
  const int spo = prow * 32 + (((pm4 >> 1) ^ ((prow >> 1) & 3))) * 8 + (pm4 & 1) * 4;
  f32x4 acc[2][4] = {};

  for (int t = -1; t < 64; ++t) {
    const int nx = t + 1;
    float4 pl;
    if (nx < 64) {
      const int m0 = nx * 32;
#pragma unroll
      for (int p = 0; p < 4; p++) {
        int u = tid + p * 256;
        int d = u >> 2;
        int q = (u & 3) ^ ((u >> 3) & 3);
        gll16(Vb + (size_t)d * NN + m0 + q * 8,
              &sV[nx & 1][0] + (size_t)(w * 64 + p * 256) * 8);
      }
      pl = *(const float4*)(slab + (size_t)prow * NN + m0 + pm4 * 4);
    }
    if (t >= 0) {
      const int cur = t & 1;
      f16x8 af[2], bf[4];
#pragma unroll
      for (int i = 0; i < 2; i++)
        af[i] = *(const f16x8*)(&sP[cur][(i * 16 + (l & 15)) * 32 + fq]);
#pragma unroll
      for (int j = 0; j < 4; j++)
        bf[j] = *(const f16x8*)(&sV[cur][(w * 64 + j * 16 + (l & 15)) * 32 + fq]);
#pragma unroll
      for (int i = 0; i < 2; i++)
#pragma unroll
        for (int j = 0; j < 4; j++)
          acc[i][j] = mfma16(af[i], bf[j], acc[i][j]);
    }
    if (nx < 64) {
      const int m0 = nx * 32;
      float e0 = __expf(pl.x) * myinv, e1 = __expf(pl.y) * myinv;
      float e2 = __expf(pl.z) * myinv, e3 = __expf(pl.w) * myinv;
      float4 ov = {e0, e1, e2, e3};
      *(float4*)(slab + (size_t)prow * NN + m0 + pm4 * 4) = ov;
      __align__(8) f16 tmp[4] = {(f16)e0, (f16)e1, (f16)e2, (f16)e3};
      *(uint2*)(&sP[nx & 1][spo]) = *(const uint2*)tmp;
    }
    __syncthreads();
  }

  // z = exp_map0(pad(agg)); rows fully within this block.
  const int rl4 = (l >> 4) * 4, cl = l & 15;
  float s2[2][4];
#pragma unroll
  for (int i = 0; i < 2; i++)
#pragma unroll
    for (int r = 0; r < 4; r++) {
      float s = 0.f;
#pragma unroll
      for (int j = 0; j < 4; j++) s = fmaf(acc[i][j][r], acc[i][j][r], s);
#pragma unroll
      for (int m = 1; m < 16; m <<= 1) s += __shfl_xor(s, m);
      s2[i][r] = s;
    }
  if (cl == 0) {
#pragma unroll
    for (int i = 0; i < 2; i++)
#pragma unroll
      for (int r = 0; r < 4; r++)
        zsum[w][i * 16 + rl4 + r] = s2[i][r];
  }
  __syncthreads();
  if (tid < 32) {
    float n2 = zsum[0][tid] + zsum[1][tid] + zsum[2][tid] + zsum[3][tid];
    float nn = sqrtf(fmaxf(n2, EPSF));
    zsc[tid] = sinhf(nn) / nn;
    z[(size_t)(b * NN + row0 + tid) * DP1] = coshf(nn);
  }
  __syncthreads();
#pragma unroll
  for (int i = 0; i < 2; i++)
#pragma unroll
    for (int r = 0; r < 4; r++) {
      const int row = i * 16 + rl4 + r;
      const float sc = zsc[row];
      const size_t zb = (size_t)(b * NN + row0 + row) * DP1 + 1;
#pragma unroll
      for (int j = 0; j < 4; j++)
        z[zb + w * 64 + j * 16 + cl] = acc[i][j][r] * sc;
    }
}

// ---------------- launch -----------------------------------------------------
extern "C" void kernel_launch(void* const* d_in, const int* in_sizes, int n_in,
                              void* d_out, int out_size, void* d_ws, size_t ws_size,
                              hipStream_t stream) {
  const float* x   = (const float*)d_in[0];
  const float* xv  = (const float*)d_in[1];
  const float* Wq  = (const float*)d_in[2];
  const float* bq  = (const float*)d_in[3];
  const float* Wk  = (const float*)d_in[4];
  const float* bk  = (const float*)d_in[5];
  const float* Wv  = (const float*)d_in[6];
  const float* bv  = (const float*)d_in[7];
  const float* tau = (const float*)d_in[8];
  float* out = (float*)d_out;
  char* ws = (char*)d_ws;

  const size_t TD2 = (size_t)TT * DD * 2;   // 8 MB f16 panel

  f16*   qh     = (f16*)(ws);               // GEMM1 out, scaled in place
  f16*   kh     = (f16*)(ws + TD2);
  f16*   qvh    = (f16*)(ws + 2 * TD2);
  f16*   kvh    = (f16*)(ws + 3 * TD2);
  f16*   vT     = (f16*)(ws + 4 * TD2);
  f16*   xtan_h = (f16*)(ws + 5 * TD2);
  f16*   vel0_h = (f16*)(ws + 6 * TD2);
  f16*   Wh     = (f16*)(ws + 7 * TD2);
  float* psum   = (float*)(ws + 7 * TD2 + 3 * DD * DD * 2);        // [8][32][2048]
  float* q0     = psum + (size_t)BB * 32 * NN;
  float* k0v    = q0 + TT;
  float* q_sq   = q0 + 2 * TT;
  float* k_sq   = q0 + 3 * TT;

  float* z_out    = out;
  float* attn_out = out + (size_t)TT * DP1;
  float* xtan_out = attn_out + (size_t)BB * NN * NN;

  prep_kernel<<<TT, 256, 0, stream>>>(x, xv, xtan_out, xtan_h, vel0_h);
  wcast_kernel<<<dim3(DD * DD / 256, 3), 256, 0, stream>>>(Wq, Wk, Wv, Wh);

  // fused x_tan GEMM: N = 768 = [q_s | k_s | vT]
  gemm_mfma<<<dim3(TT / 128, 6), 256, 0, stream>>>(
      xtan_h, Wh, qh, kh, vT, bq, bk, bv, 0, 0, 1);

  // fused vel GEMM: N = 512 = [q_vel | k_vel]
  gemm_mfma<<<dim3(TT / 128, 4), 256, 0, stream>>>(
      vel0_h, Wh, qvh, kvh, nullptr, bq, bk, nullptr, 0, 0, 0);

  scale_kernel<<<TT, 256, 0, stream>>>(qh, kh, qvh, kvh, q0, k0v, q_sq, k_sq);

  logits_mfma<<<NN / 128 * NN / 128 * BB, 256, 0, stream>>>(
      qh, kh, qvh, kvh, q0, k0v, q_sq, k_sq, tau, attn_out, psum);

  pv_fused<<<NN / 32 * BB, 256, 0, stream>>>(psum, vT, attn_out, z_out);
}

// Round 6
// 205.561 us; speedup vs baseline: 5.5505x; 1.2579x over previous
//
#include <hip/hip_runtime.h>
#include <math.h>

#define BB 8
#define NN 2048
#define DD 256
#define TT (BB*NN)      // 16384 tokens
#define DP1 257
#define EPSF 1e-6f

typedef _Float16 f16;
typedef __attribute__((ext_vector_type(8))) _Float16 f16x8;
typedef __attribute__((ext_vector_type(4))) float f32x4;

#define BAR() asm volatile("s_barrier" ::: "memory")
#define WAIT_VM(N) asm volatile("s_waitcnt vmcnt(" #N ")" ::: "memory")
#define WAIT_LGKM0() asm volatile("s_waitcnt lgkmcnt(0)" ::: "memory")

__device__ __forceinline__ f32x4 mfma16(f16x8 a, f16x8 b, f32x4 c) {
  return __builtin_amdgcn_mfma_f32_16x16x32_f16(a, b, c, 0, 0, 0);
}
// async global->LDS, 16B/lane; dest = wave-uniform base + lane*16.
__device__ __forceinline__ void gll16(const f16* g, f16* l) {
  __builtin_amdgcn_global_load_lds(
      (const __attribute__((address_space(1))) void*)g,
      (__attribute__((address_space(3))) void*)l, 16, 0, 0);
}

__device__ __forceinline__ float wave_sum(float v) {
#pragma unroll
  for (int m = 1; m < 64; m <<= 1) v += __shfl_xor(v, m);
  return v;
}

// ---------------- K1: one wave per token, shfl-only ----------------
__global__ __launch_bounds__(256) void prep_kernel(
    const float* __restrict__ x, const float* __restrict__ xv,
    float* __restrict__ xtan, f16* __restrict__ xtan_h, f16* __restrict__ vel0_h) {
  const int w = threadIdx.x >> 6, l = threadIdx.x & 63;
  const int tok = blockIdx.x * 4 + w;
  const float* xr = x  + (size_t)tok * DP1;
  const float* vr = xv + (size_t)tok * DP1;
  float x0 = xr[0];
  float sp[4];
  float ss = 0.f;
#pragma unroll
  for (int j = 0; j < 4; j++) { sp[j] = xr[1 + l + 64 * j]; ss = fmaf(sp[j], sp[j], ss); }
  ss = wave_sum(ss);
  float n  = sqrtf(fmaxf(ss, EPSF));
  float dd = acoshf(fmaxf(x0, 1.f + EPSF));
  float scl = dd / n;
  float coef = -vr[0] / (1.f + x0);
  const size_t base = (size_t)tok * DD;
#pragma unroll
  for (int j = 0; j < 4; j++) {
    float xt = scl * sp[j];
    xtan[base + l + 64 * j] = xt;
    xtan_h[base + l + 64 * j] = (f16)xt;
    vel0_h[base + l + 64 * j] = (f16)(vr[1 + l + 64 * j] + coef * sp[j]);
  }
}

// ---------------- weight cast fp32 -> f16, Wh = [Wq;Wk;Wv] ------------------
__global__ __launch_bounds__(256) void wcast_kernel(
    const float* __restrict__ Wq, const float* __restrict__ Wk,
    const float* __restrict__ Wv, f16* __restrict__ Wh) {
  const int m = blockIdx.y;
  const int i = blockIdx.x * 256 + threadIdx.x;
  const float* W = (m == 0) ? Wq : ((m == 1) ? Wk : Wv);
  Wh[(size_t)m * DD * DD + i] = (f16)W[i];
}

// ---------------- merged MFMA GEMM, 128x128 tile, counted vmcnt --------------
// grid (TT/128, 10): 5 segs of 256 cols: [q_s|k_s|vT] from xtan, [qv|kv] from vel0
__global__ __launch_bounds__(256, 2) void gemm_mfma(
    const f16* __restrict__ xtan_h, const f16* __restrict__ vel0_h,
    const f16* __restrict__ Wh,
    f16* __restrict__ qh, f16* __restrict__ kh, f16* __restrict__ vT,
    f16* __restrict__ qvh, f16* __restrict__ kvh,
    const float* __restrict__ bq, const float* __restrict__ bk,
    const float* __restrict__ bv) {
  __shared__ __align__(16) f16 sA[2 * 4096];
  __shared__ __align__(16) f16 sB[2 * 4096];
  const int tid = threadIdx.x;
  const int bm = blockIdx.x * 128;
  const int bn = blockIdx.y * 128;
  const int seg = bn >> 8;                 // 0..4
  const int w = tid >> 6, l = tid & 63;
  const int wr = w >> 1, wc = w & 1;
  f32x4 acc[4][4] = {};
  const f16* Ab = ((seg < 3) ? xtan_h : vel0_h) + (size_t)bm * DD;
  const f16* Bb = Wh + (size_t)((seg < 3) ? bn : (bn - 768)) * DD;

  auto stage = [&](int nx) {
    const int half = nx & 1, k0 = nx * 32;
#pragma unroll
    for (int p = 0; p < 2; p++) {
      int u = tid + p * 256;
      int row = u >> 2;
      int q = (u & 3) ^ ((u >> 3) & 3);
      size_t go = (size_t)row * DD + k0 + q * 8;
      size_t lb = (size_t)half * 4096 + (size_t)(w * 64 + p * 256) * 8;
      gll16(Ab + go, sA + lb);
      gll16(Bb + go, sB + lb);
    }
  };

  stage(0);
  const int fq = ((l >> 4) ^ ((l >> 1) & 3)) * 8;
  for (int kt = 0; kt < 8; ++kt) {
    if (kt < 7) { stage(kt + 1); WAIT_VM(4); }
    else        { WAIT_VM(0); }
    BAR();
    const int co = (kt & 1) * 4096;
    f16x8 af[4], bf[4];
#pragma unroll
    for (int i = 0; i < 4; i++)
      af[i] = *(const f16x8*)(sA + co + (wr * 64 + i * 16 + (l & 15)) * 32 + fq);
#pragma unroll
    for (int j = 0; j < 4; j++)
      bf[j] = *(const f16x8*)(sB + co + (wc * 64 + j * 16 + (l & 15)) * 32 + fq);
#pragma unroll
    for (int i = 0; i < 4; i++)
#pragma unroll
      for (int j = 0; j < 4; j++)
        acc[i][j] = mfma16(af[i], bf[j], acc[i][j]);
    BAR();
  }

  f16* optr = (seg == 0) ? qh : (seg == 1) ? kh : (seg == 2) ? vT : (seg == 3) ? qvh : kvh;
  const float* bias = (seg == 0 || seg == 3) ? bq : (seg == 1 || seg == 4) ? bk : bv;
  const int ot = (seg == 2) ? 1 : 0;
  const int rl = (l >> 4) * 4, cl = l & 15;
#pragma unroll
  for (int i = 0; i < 4; i++) {
#pragma unroll
    for (int j = 0; j < 4; j++) {
      const int col = (bn & 255) + wc * 64 + j * 16 + cl;
      const float bvv = bias[col];
      const int row0 = bm + wr * 64 + i * 16 + rl;
      if (ot == 0) {
#pragma unroll
        for (int r = 0; r < 4; r++)
          optr[(size_t)(row0 + r) * DD + col] = (f16)(acc[i][j][r] + bvv);
      } else {
        __align__(8) f16 tmp[4];
#pragma unroll
        for (int r = 0; r < 4; r++) tmp[r] = (f16)(acc[i][j][r] + bvv);
        f16* dst = optr + ((size_t)((row0 >> 11) * DD + col)) * NN + (row0 & (NN - 1));
        *(uint2*)dst = *(const uint2*)tmp;
      }
    }
  }
}

// ---------------- scale: one wave per token, shfl-only -----------------------
__global__ __launch_bounds__(256) void scale_kernel(
    f16* __restrict__ qh, f16* __restrict__ kh,
    const f16* __restrict__ qvh, const f16* __restrict__ kvh,
    float* __restrict__ q0, float* __restrict__ k0v,
    float* __restrict__ q_sq, float* __restrict__ k_sq) {
  const int w = threadIdx.x >> 6, l = threadIdx.x & 63;
  const int tok = blockIdx.x * 4 + w;
  const size_t base = (size_t)tok * DD;
  float q[4], k[4];
  float sq = 0.f, sk = 0.f, svq = 0.f, svk = 0.f;
#pragma unroll
  for (int j = 0; j < 4; j++) {
    size_t off = base + l + 64 * j;
    q[j] = (float)qh[off];
    k[j] = (float)kh[off];
    float qv = (float)qvh[off], kv = (float)kvh[off];
    sq = fmaf(q[j], q[j], sq);
    sk = fmaf(k[j], k[j], sk);
    svq = fmaf(qv, qv, svq);
    svk = fmaf(kv, kv, svk);
  }
  sq = wave_sum(sq); sk = wave_sum(sk);
  svq = wave_sum(svq); svk = wave_sum(svk);
  float nq = sqrtf(fmaxf(sq, EPSF));
  float nk = sqrtf(fmaxf(sk, EPSF));
  float scq = sinhf(nq) / nq, sck = sinhf(nk) / nk;
#pragma unroll
  for (int j = 0; j < 4; j++) {
    size_t off = base + l + 64 * j;
    qh[off] = (f16)(q[j] * scq);
    kh[off] = (f16)(k[j] * sck);
  }
  if (l == 0) {
    q0[tok] = coshf(nq);
    k0v[tok] = coshf(nk);
    q_sq[tok] = svq;
    k_sq[tok] = svk;
  }
}

// ---------------- logits: dual MFMA, counted vmcnt; stores UNNORM-EXP --------
__global__ __launch_bounds__(256, 2) void logits_mfma(
    const f16* __restrict__ qh, const f16* __restrict__ kh,
    const f16* __restrict__ qvh, const f16* __restrict__ kvh,
    const float* __restrict__ q0a, const float* __restrict__ k0a,
    const float* __restrict__ qsqa, const float* __restrict__ ksqa,
    const float* __restrict__ tau, float* __restrict__ attn,
    float* __restrict__ psum) {
  __shared__ __align__(16) f16 sQ[2*4096], sK[2*4096], sQv[2*4096], sKv[2*4096];
  const int tid = threadIdx.x;
  const int bid = blockIdx.x;
  const int b = bid & 7;
  const int bq = ((bid >> 3) & 15) * 128;   // queries
  const int kti = bid >> 7;                 // key-tile index
  const int bk = kti * 128;                 // keys
  const size_t tb = (size_t)b * NN;
  const f16* Q  = qh  + (tb + bq) * DD;
  const f16* Kp = kh  + (tb + bk) * DD;
  const f16* Qv = qvh + (tb + bq) * DD;
  const f16* Kv = kvh + (tb + bk) * DD;
  const int w = tid >> 6, l = tid & 63;
  const int wr = w >> 1, wc = w & 1;
  f32x4 accq[4][4] = {}, accv[4][4] = {};

  auto stage = [&](int nx) {
    const int half = nx & 1, k0 = nx * 32;
#pragma unroll
    for (int p = 0; p < 2; p++) {
      int u = tid + p * 256;
      int row = u >> 2;
      int q = (u & 3) ^ ((u >> 3) & 3);
      size_t go = (size_t)row * DD + k0 + q * 8;
      size_t lb = (size_t)half * 4096 + (size_t)(w * 64 + p * 256) * 8;
      gll16(Kp + go, sK  + lb);
      gll16(Q  + go, sQ  + lb);
      gll16(Kv + go, sKv + lb);
      gll16(Qv + go, sQv + lb);
    }
  };

  stage(0);
  const int fq = ((l >> 4) ^ ((l >> 1) & 3)) * 8;
  for (int kt = 0; kt < 8; ++kt) {
    if (kt < 7) { stage(kt + 1); WAIT_VM(8); }
    else        { WAIT_VM(0); }
    BAR();
    const int co = (kt & 1) * 4096;
    {
      f16x8 ak[4], bqf[4];
#pragma unroll
      for (int i = 0; i < 4; i++)
        ak[i] = *(const f16x8*)(sK + co + (wr * 64 + i * 16 + (l & 15)) * 32 + fq);
#pragma unroll
      for (int j = 0; j < 4; j++)
        bqf[j] = *(const f16x8*)(sQ + co + (wc * 64 + j * 16 + (l & 15)) * 32 + fq);
#pragma unroll
      for (int i = 0; i < 4; i++)
#pragma unroll
        for (int j = 0; j < 4; j++)
          accq[i][j] = mfma16(ak[i], bqf[j], accq[i][j]);
    }
    {
      f16x8 ak[4], bqf[4];
#pragma unroll
      for (int i = 0; i < 4; i++)
        ak[i] = *(const f16x8*)(sKv + co + (wr * 64 + i * 16 + (l & 15)) * 32 + fq);
#pragma unroll
      for (int j = 0; j < 4; j++)
        bqf[j] = *(const f16x8*)(sQv + co + (wc * 64 + j * 16 + (l & 15)) * 32 + fq);
#pragma unroll
      for (int i = 0; i < 4; i++)
#pragma unroll
        for (int j = 0; j < 4; j++)
          accv[i][j] = mfma16(ak[i], bqf[j], accv[i][j]);
    }
    BAR();
  }

  const int rl = (l >> 4) * 4, cl = l & 15;
  const float invt = 1.f / fmaxf(tau[0], 1e-3f);
  const float cc = invt * 0.4804530139182014f;   // ln2^2
  float q0r[4], qsr[4];
  float4 k0c[4], ksc[4];
#pragma unroll
  for (int j = 0; j < 4; j++) {
    const int qq = bq + wc * 64 + j * 16 + cl;
    q0r[j] = q0a[tb + qq];
    qsr[j] = qsqa[tb + qq];
  }
#pragma unroll
  for (int i = 0; i < 4; i++) {
    const int kk = bk + wr * 64 + i * 16 + rl;
    k0c[i] = *(const float4*)(k0a + tb + kk);
    ksc[i] = *(const float4*)(ksqa + tb + kk);
  }
  const size_t obase = (size_t)b * NN * NN;
#pragma unroll
  for (int j = 0; j < 4; j++) {
    const int qq = bq + wc * 64 + j * 16 + cl;
    const float q0 = q0r[j], qs = qsr[j];
    float es = 0.f;
#pragma unroll
    for (int i = 0; i < 4; i++) {
      const int kk = bk + wr * 64 + i * 16 + rl;
      const float* k0p = (const float*)&k0c[i];
      const float* ksp = (const float*)&ksc[i];
      float4 o;
      float* op = (float*)&o;
#pragma unroll
      for (int r = 0; r < 4; r++) {
        float xv = fmaxf(fmaf(q0, k0p[r], -accq[i][j][r]), 1.f + EPSF);
        float s = sqrtf(fmaf(xv, xv, -1.f));
        float lg = __log2f(xv + s);
        float pen = fmaxf(fmaf(-2.f, accv[i][j][r], qs + ksp[r]), 0.f);
        float lo = fmaf(-cc * lg, lg, -pen);
        float ex = __expf(lo);          // store unnormalized exp
        op[r] = ex;
        es += ex;
      }
      *(float4*)(attn + obase + (size_t)qq * NN + kk) = o;
    }
    es += __shfl_xor(es, 16);
    es += __shfl_xor(es, 32);
    if ((l >> 4) == 0)
      psum[((size_t)(b * 16 + kti) * 2 + wr) * NN + qq] = es;
  }
}

// ---------------- fused normalize + PV + exp-map (z) -------------------------
// attn holds unnorm-exp fp32 on entry; normalized fp32 on exit.
// V triple-buffered (prefetch distance 2), P two-register T14 pipeline.
__global__ __launch_bounds__(256, 2) void pv_fused(
    const float* __restrict__ psum, const f16* __restrict__ vT,
    float* __restrict__ attn, float* __restrict__ z) {
  __shared__ __align__(16) f16 sP[2][32 * 32];
  __shared__ __align__(16) f16 sV[3][256 * 32];
  __shared__ float invs_l[32];
  __shared__ float zsum[4][32];
  __shared__ float zsc[32];
  const int tid = threadIdx.x;
  const int bid = blockIdx.x;
  const int b = bid & 7;
  const int row0 = (bid >> 3) * 32;
  const int w = tid >> 6, l = tid & 63;
  float* slab = attn + ((size_t)b * NN + row0) * NN;
  const f16* Vb = vT + (size_t)b * DD * NN;

  if (tid < 32) {
    float s = 0.f;
#pragma unroll 4
    for (int p = 0; p < 32; p++) s += psum[((size_t)b * 32 + p) * NN + row0 + tid];
    invs_l[tid] = 1.f / s;
  }
  __syncthreads();
  const int prow = tid >> 3, pm4 = tid & 7;
  const float myinv = invs_l[prow];
  const int fq = ((l >> 4) ^ ((l >> 1) & 3)) * 8;
  const int spo = prow * 32 + ((pm4 >> 1) ^ ((prow >> 1) & 3)) * 8 + (pm4 & 1) * 4;
  f32x4 acc[2][4] = {};
  float4 pA, pB;

#define STAGEV(nx, vb) do { const int m0_ = (nx) * 32;                          \
    _Pragma("unroll")                                                           \
    for (int p_ = 0; p_ < 4; p_++) {                                            \
      int u_ = tid + p_ * 256;                                                  \
      int d_ = u_ >> 2;                                                         \
      int q_ = (u_ & 3) ^ ((u_ >> 3) & 3);                                      \
      gll16(Vb + (size_t)d_ * NN + m0_ + q_ * 8,                                \
            (f16*)&sV[vb][0] + (size_t)(w * 64 + p_ * 256) * 8);                \
    } } while (0)
#define LOADP(nx, reg) do {                                                     \
    reg = *(const float4*)(slab + (size_t)prow * NN + (nx) * 32 + pm4 * 4);     \
  } while (0)
#define USEP(nx, reg) do {                                                      \
    float e0_ = reg.x * myinv, e1_ = reg.y * myinv;                             \
    float e2_ = reg.z * myinv, e3_ = reg.w * myinv;                             \
    float4 ov_ = {e0_, e1_, e2_, e3_};                                          \
    *(float4*)(slab + (size_t)prow * NN + (nx) * 32 + pm4 * 4) = ov_;           \
    __align__(8) f16 tmp_[4] = {(f16)e0_, (f16)e1_, (f16)e2_, (f16)e3_};        \
    *(uint2*)(&sP[(nx) & 1][spo]) = *(const uint2*)tmp_;                        \
  } while (0)
#define COMPUTE(t, vb) do {                                                     \
    f16x8 af_[2], bf_[4];                                                       \
    _Pragma("unroll")                                                           \
    for (int i_ = 0; i_ < 2; i_++)                                              \
      af_[i_] = *(const f16x8*)(&sP[(t) & 1][(i_ * 16 + (l & 15)) * 32 + fq]);  \
    _Pragma("unroll")                                                           \
    for (int j_ = 0; j_ < 4; j_++)                                              \
      bf_[j_] = *(const f16x8*)((const f16*)&sV[vb][0] +                        \
                                (w * 64 + j_ * 16 + (l & 15)) * 32 + fq);       \
    _Pragma("unroll")                                                           \
    for (int i_ = 0; i_ < 2; i_++)                                              \
      _Pragma("unroll")                                                         \
      for (int j_ = 0; j_ < 4; j_++)                                            \
        acc[i_][j_] = mfma16(af_[i_], bf_[j_], acc[i_][j_]);                    \
  } while (0)

  // prologue: tiles 0,1 in flight
  STAGEV(0, 0); LOADP(0, pA);
  STAGEV(1, 1); LOADP(1, pB);
  WAIT_VM(5);          // V0 + P0 done (V1, P1 still in flight)
  USEP(0, pA);
  WAIT_LGKM0();
  BAR();

  int vb0 = 0;         // = t%3 for even t of the pair
  for (int tt = 0; tt < 32; ++tt) {
    {  // t even: NEXT preg = pB, FAR = pA
      const int t = 2 * tt;
      const int vb_t = vb0;
      const int vb_s = (vb0 + 2 > 2) ? vb0 - 1 : vb0 + 2;   // (t+2)%3
      if (t < 62) { STAGEV(t + 2, vb_s); LOADP(t + 2, pA); WAIT_VM(5); }
      else        { WAIT_VM(1); }                            // t==62
      if (t < 63) USEP(t + 1, pB);
      COMPUTE(t, vb_t);
      WAIT_LGKM0();
      BAR();
    }
    {  // t odd: NEXT preg = pA, FAR = pB
      const int t = 2 * tt + 1;
      const int vb_t = (vb0 + 1 > 2) ? vb0 - 2 : vb0 + 1;   // t%3
      const int vb_s = vb0;                                  // (t+2)%3
      if (t < 62)      { STAGEV(t + 2, vb_s); LOADP(t + 2, pB); WAIT_VM(5); }
      else if (t == 62){ WAIT_VM(1); }
      else             { WAIT_VM(0); }                       // t==63
      if (t < 63) USEP(t + 1, pA);
      COMPUTE(t, vb_t);
      WAIT_LGKM0();
      BAR();
    }
    vb0 = (vb0 + 2 > 2) ? vb0 - 1 : vb0 + 2;
  }
#undef STAGEV
#undef LOADP
#undef USEP
#undef COMPUTE

  // z = exp_map0(pad(agg)); acc is already normalized (sP held normalized P).
  const int rl4 = (l >> 4) * 4, cl = l & 15;
  float s2[2][4];
#pragma unroll
  for (int i = 0; i < 2; i++)
#pragma unroll
    for (int r = 0; r < 4; r++) {
      float s = 0.f;
#pragma unroll
      for (int j = 0; j < 4; j++) s = fmaf(acc[i][j][r], acc[i][j][r], s);
#pragma unroll
      for (int m = 1; m < 16; m <<= 1) s += __shfl_xor(s, m);
      s2[i][r] = s;
    }
  if (cl == 0) {
#pragma unroll
    for (int i = 0; i < 2; i++)
#pragma unroll
      for (int r = 0; r < 4; r++)
        zsum[w][i * 16 + rl4 + r] = s2[i][r];
  }
  __syncthreads();
  if (tid < 32) {
    float n2 = zsum[0][tid] + zsum[1][tid] + zsum[2][tid] + zsum[3][tid];
    float nn = sqrtf(fmaxf(n2, EPSF));
    zsc[tid] = sinhf(nn) / nn;
    z[(size_t)(b * NN + row0 + tid) * DP1] = coshf(nn);
  }
  __syncthreads();
#pragma unroll
  for (int i = 0; i < 2; i++)
#pragma unroll
    for (int r = 0; r < 4; r++) {
      const int row = i * 16 + rl4 + r;
      const float sc = zsc[row];
      const size_t zb = (size_t)(b * NN + row0 + row) * DP1 + 1;
#pragma unroll
      for (int j = 0; j < 4; j++)
        z[zb + w * 64 + j * 16 + cl] = acc[i][j][r] * sc;
    }
}

// ---------------- launch -----------------------------------------------------
extern "C" void kernel_launch(void* const* d_in, const int* in_sizes, int n_in,
                              void* d_out, int out_size, void* d_ws, size_t ws_size,
                              hipStream_t stream) {
  const float* x   = (const float*)d_in[0];
  const float* xv  = (const float*)d_in[1];
  const float* Wq  = (const float*)d_in[2];
  const float* bq  = (const float*)d_in[3];
  const float* Wk  = (const float*)d_in[4];
  const float* bk  = (const float*)d_in[5];
  const float* Wv  = (const float*)d_in[6];
  const float* bv  = (const float*)d_in[7];
  const float* tau = (const float*)d_in[8];
  float* out = (float*)d_out;
  char* ws = (char*)d_ws;

  const size_t TD2 = (size_t)TT * DD * 2;   // 8 MB f16 panel

  f16*   qh     = (f16*)(ws);               // GEMM out, scaled in place
  f16*   kh     = (f16*)(ws + TD2);
  f16*   qvh    = (f16*)(ws + 2 * TD2);
  f16*   kvh    = (f16*)(ws + 3 * TD2);
  f16*   vT     = (f16*)(ws + 4 * TD2);
  f16*   xtan_h = (f16*)(ws + 5 * TD2);
  f16*   vel0_h = (f16*)(ws + 6 * TD2);
  f16*   Wh     = (f16*)(ws + 7 * TD2);
  float* psum   = (float*)(ws + 7 * TD2 + 3 * DD * DD * 2);        // [8][32][2048]
  float* q0     = psum + (size_t)BB * 32 * NN;
  float* k0v    = q0 + TT;
  float* q_sq   = q0 + 2 * TT;
  float* k_sq   = q0 + 3 * TT;

  float* z_out    = out;
  float* attn_out = out + (size_t)TT * DP1;
  float* xtan_out = attn_out + (size_t)BB * NN * NN;

  prep_kernel<<<TT / 4, 256, 0, stream>>>(x, xv, xtan_out, xtan_h, vel0_h);
  wcast_kernel<<<dim3(DD * DD / 256, 3), 256, 0, stream>>>(Wq, Wk, Wv, Wh);

  // merged GEMM: 5 segs = [q_s | k_s | vT | q_vel | k_vel]
  gemm_mfma<<<dim3(TT / 128, 10), 256, 0, stream>>>(
      xtan_h, vel0_h, Wh, qh, kh, vT, qvh, kvh, bq, bk, bv);

  scale_kernel<<<TT / 4, 256, 0, stream>>>(qh, kh, qvh, kvh, q0, k0v, q_sq, k_sq);

  logits_mfma<<<NN / 128 * NN / 128 * BB, 256, 0, stream>>>(
      qh, kh, qvh, kvh, q0, k0v, q_sq, k_sq, tau, attn_out, psum);

  pv_fused<<<NN / 32 * BB, 256, 0, stream>>>(psum, vT, attn_out, z_out);
}